// Round 8
// baseline (24339.511 us; speedup 1.0000x reference)
//
#include <hip/hip_runtime.h>
#include <hip/hip_bf16.h>
#include <math.h>

// Problem constants: V=32000, D=256, H=256, L=2, C=2, B=64, T=1024, PAD=0
namespace {
constexpr int Bn = 64;
constexpr int Tn = 1024;
constexpr int Dn = 256;
constexpr int Hn = 256;
}

typedef __attribute__((ext_vector_type(8))) short short8;
typedef __attribute__((ext_vector_type(4))) float f32x4;

template <typename T>
__device__ __forceinline__ float ldf(const T* p, long i);
template <>
__device__ __forceinline__ float ldf<float>(const float* p, long i) { return p[i]; }
template <>
__device__ __forceinline__ float ldf<__hip_bfloat16>(const __hip_bfloat16* p, long i) {
  return __bfloat162float(p[i]);
}

__device__ __forceinline__ float sigmf(float x) { return 1.0f / (1.0f + __expf(-x)); }
__device__ __forceinline__ float tanh_fast(float x) {
  return 1.0f - 2.0f / (__expf(2.0f * x) + 1.0f);
}

// ---------------------------------------------------------------------------
// Dtype detector (validated round 2: flag=1 -> f32 inputs).
// ---------------------------------------------------------------------------
__global__ void k_detect(const unsigned short* __restrict__ e, int* __restrict__ flag) {
  __shared__ int sbuf[256];
  int bad = 0;
  for (int i = threadIdx.x; i < 4096; i += 256) {
    const unsigned short v = e[i];
    const int ex = (v >> 7) & 0xFF;
    bad += (ex >= 137) ? 1 : 0;
  }
  sbuf[threadIdx.x] = bad;
  __syncthreads();
  for (int s = 128; s > 0; s >>= 1) {
    if (threadIdx.x < s) sbuf[threadIdx.x] += sbuf[threadIdx.x + s];
    __syncthreads();
  }
  if (threadIdx.x == 0) flag[0] = (sbuf[0] > 64) ? 1 : 0;
}

__global__ void k_lengths(const int* __restrict__ x, int* __restrict__ len) {
  const int b = blockIdx.x;
  int cnt = 0;
  for (int t = threadIdx.x; t < Tn; t += blockDim.x) cnt += (x[b * Tn + t] != 0) ? 1 : 0;
  __shared__ int sbuf[256];
  sbuf[threadIdx.x] = cnt;
  __syncthreads();
  for (int s = 128; s > 0; s >>= 1) {
    if (threadIdx.x < s) sbuf[threadIdx.x] += sbuf[threadIdx.x + s];
    __syncthreads();
  }
  if (threadIdx.x == 0) len[b] = sbuf[0];
}

// ===========================================================================
// FAST PATH
// ===========================================================================

// biases -> f32 [4][1024] (order: f0,b0,f1,b1).
__global__ void k_prep_small(const void* b0f, const void* b0b, const void* b1f, const void* b1b,
                             const int* __restrict__ flag, float* __restrict__ biasbuf) {
  const int tid = threadIdx.x;
  const bool isf32 = flag[0] != 0;
  for (int idx = tid; idx < 4096; idx += 256) {
    const int j = idx >> 10, col = idx & 1023;
    const void* src = (j == 0) ? b0f : (j == 1) ? b0b : (j == 2) ? b1f : b1b;
    biasbuf[idx] = isf32 ? ((const float*)src)[col]
                         : __bfloat162float(((const __hip_bfloat16*)src)[col]);
  }
}

// Transpose+convert W[(H+XK) x 1024] -> WhT bf16 [1024][256], WxT bf16 [1024][XK].
__global__ void k_prepw(const void* W0, const void* W1, const void* W2, const void* W3,
                        const int* __restrict__ flag, __hip_bfloat16* __restrict__ whT,
                        __hip_bfloat16* __restrict__ wxT0, __hip_bfloat16* __restrict__ wxT1) {
  const int j = blockIdx.z;
  const int rows = (j < 2) ? 512 : 768;
  const int bx = blockIdx.x;
  if (bx * 64 >= rows) return;
  const int by = blockIdx.y;
  const void* W = (j == 0) ? W0 : (j == 1) ? W1 : (j == 2) ? W2 : W3;
  const bool isf32 = flag[0] != 0;
  __shared__ float tile[64][65];
  const int tid = threadIdx.x;
  const int c = tid & 63, r4 = tid >> 6;
#pragma unroll
  for (int rep = 0; rep < 16; ++rep) {
    const int rr = r4 * 16 + rep;
    const size_t idx = (size_t)(bx * 64 + rr) * 1024 + by * 64 + c;
    tile[rr][c] = isf32 ? ((const float*)W)[idx]
                        : __bfloat162float(((const __hip_bfloat16*)W)[idx]);
  }
  __syncthreads();
  const int kk = tid & 63;
#pragma unroll
  for (int rep = 0; rep < 16; ++rep) {
    const int a = r4 * 16 + rep;
    const int n = by * 64 + a;
    const int k = bx * 64 + kk;
    const __hip_bfloat16 v = __float2bfloat16(tile[kk][a]);
    if (k < 256) {
      whT[(size_t)j * (1024 * 256) + (size_t)n * 256 + k] = v;
    } else {
      const int k2 = k - 256;
      if (j < 2)
        wxT0[(size_t)j * (1024 * 256) + (size_t)n * 256 + k2] = v;
      else
        wxT1[(size_t)(j - 2) * (1024 * 512) + (size_t)n * 512 + k2] = v;
    }
  }
}

// ---------------------------------------------------------------------------
// xproj GEMM v5 (validated round 7): 128x128 tile, B in LDS, batch-split
// consumer layout. v5.1: output stores and layer-1 seq0 A-reads are
// NON-TEMPORAL (stream-once data; keep it out of L2 so the lstm's weight
// set stays resident on each XCD).
//   off_bf16 = (((d*Tc+tl)*4 + beta)*8 + ch)*2048 + tid*8 + elem
// Producer mapping (verified, PASS round 7):
//   tl = bx*2+(w>>1); beta = (w&1)*2+mt2; ch = (by>>1)*2+(ntp&1);
//   tid_c = ((by&1)*2+(ntp>>1))*64+quad*16+l16; elem = r / 4+r.
// ---------------------------------------------------------------------------
template <int K, bool GATHER>
__launch_bounds__(256, 2)
__global__ void k_xproj3(const int* __restrict__ x, const void* __restrict__ E,
                         const int* __restrict__ flag, const __hip_bfloat16* __restrict__ Af,
                         const __hip_bfloat16* __restrict__ Ab,
                         const __hip_bfloat16* __restrict__ WT,  // [2][1024][K]
                         __hip_bfloat16* __restrict__ xp,        // [2][Tc][4][8][256][8]
                         const int Mrows, const int t0f, const int t0b) {
  constexpr int KC = 256;
  __shared__ __hip_bfloat16 Btile[128][KC + 8];
  const int tix = blockIdx.x;
  const int by = tix & 7;
  const int dz = (tix >> 3) & 1;
  const int bx = tix >> 4;
  const int tid = threadIdx.x, w = tid >> 6, L = tid & 63, quad = L >> 4, l16 = L & 15;
  const __hip_bfloat16* __restrict__ WTd = WT + (size_t)dz * (1024 * K);
  __hip_bfloat16* __restrict__ o = xp + (size_t)dz * Mrows * 1024;

  f32x4 acc[2][8];
#pragma unroll
  for (int mt = 0; mt < 2; ++mt)
#pragma unroll
    for (int nt = 0; nt < 8; ++nt) {
      acc[mt][nt][0] = 0.f; acc[mt][nt][1] = 0.f; acc[mt][nt][2] = 0.f; acc[mt][nt][3] = 0.f;
    }

  const int row0 = bx * 128 + w * 32 + l16;  // a0 row; a1 = row0+16
  const __hip_bfloat16* arow0b = nullptr;
  const __hip_bfloat16* arow1b = nullptr;
  const float* arow0f = nullptr;
  const float* arow1f = nullptr;
  bool isf32 = false;
  if constexpr (GATHER) {
    isf32 = flag[0] != 0;
    const int t0 = (dz ? t0b : t0f) + (row0 >> 6), b0 = row0 & 63;
    const int r1 = row0 + 16;
    const int t1 = (dz ? t0b : t0f) + (r1 >> 6), b1 = r1 & 63;
    const int tok0 = x[b0 * Tn + t0];
    const int tok1 = x[b1 * Tn + t1];
    if (isf32) {
      arow0f = (const float*)E + (size_t)tok0 * Dn;
      arow1f = (const float*)E + (size_t)tok1 * Dn;
    } else {
      arow0b = (const __hip_bfloat16*)E + (size_t)tok0 * Dn;
      arow1b = (const __hip_bfloat16*)E + (size_t)tok1 * Dn;
    }
  } else {
    const __hip_bfloat16* A = dz ? Ab : Af;
    arow0b = A + (size_t)row0 * K;
    arow1b = A + (size_t)(row0 + 16) * K;
  }

  for (int ch = 0; ch < K / KC; ++ch) {
    if (ch) __syncthreads();
    // stage B chunk: 128 cols x 256 shorts
#pragma unroll
    for (int it = 0; it < 16; ++it) {
      const int idx = it * 256 + tid;
      const int col = idx >> 5, seg = idx & 31;
      *(short8*)&Btile[col][seg * 8] =
          *(const short8*)(WTd + (size_t)(by * 128 + col) * K + ch * KC + seg * 8);
    }
    __syncthreads();

#pragma unroll
    for (int kc = 0; kc < 8; ++kc) {
      short8 a0, a1;
      if constexpr (GATHER) {
        if (isf32) {
#pragma unroll
          for (int jj = 0; jj < 8; ++jj) {
            __hip_bfloat16 h0 = __float2bfloat16(arow0f[kc * 32 + quad * 8 + jj]);
            __hip_bfloat16 h1 = __float2bfloat16(arow1f[kc * 32 + quad * 8 + jj]);
            a0[jj] = *(const short*)&h0;
            a1[jj] = *(const short*)&h1;
          }
        } else {
          a0 = *(const short8*)(arow0b + kc * 32 + quad * 8);
          a1 = *(const short8*)(arow1b + kc * 32 + quad * 8);
        }
      } else {
        // layer-1 A = seq0, read-once stream -> non-temporal
        a0 = __builtin_nontemporal_load(
            (const short8*)(arow0b + ch * KC + kc * 32 + quad * 8));
        a1 = __builtin_nontemporal_load(
            (const short8*)(arow1b + ch * KC + kc * 32 + quad * 8));
      }
#pragma unroll
      for (int nt = 0; nt < 8; ++nt) {
        const short8 b = *(const short8*)&Btile[nt * 16 + l16][kc * 32 + quad * 8];
        acc[0][nt] = __builtin_amdgcn_mfma_f32_16x16x32_bf16(a0, b, acc[0][nt], 0, 0, 0);
        acc[1][nt] = __builtin_amdgcn_mfma_f32_16x16x32_bf16(a1, b, acc[1][nt], 0, 0, 0);
      }
    }
  }

  // --- epilogue: batch-split consumer layout, non-temporal 16B stores ---
  {
    const int tl = bx * 2 + (w >> 1);
    const int chbase = (by >> 1) * 2;
    const int wcbase = (by & 1) * 2;
    const int tcl = quad * 16 + l16;
#pragma unroll
    for (int mt2 = 0; mt2 < 2; ++mt2) {
      const int beta = (w & 1) * 2 + mt2;
      __hip_bfloat16* __restrict__ ob = o + ((size_t)tl * 4 + beta) * 16384;
#pragma unroll
      for (int ntp = 0; ntp < 4; ++ntp) {
        const int ch_ = chbase + (ntp & 1);
        const int tid_c = (wcbase + (ntp >> 1)) * 64 + tcl;
        short8 sv;
#pragma unroll
        for (int r = 0; r < 4; ++r) {
          __hip_bfloat16 h0 = __float2bfloat16(acc[mt2][2 * ntp][r]);
          __hip_bfloat16 h1 = __float2bfloat16(acc[mt2][2 * ntp + 1][r]);
          sv[r] = *(const short*)&h0;
          sv[4 + r] = *(const short*)&h1;
        }
        __builtin_nontemporal_store(sv, (short8*)(ob + ch_ * 2048 + tid_c * 8));
      }
    }
  }
}

// ---------------------------------------------------------------------------
// Recurrent layer v9.1 -- BATCH-SPLIT (validated round 7), streaming traffic
// made NON-TEMPORAL:
//   * xproj per-step loads: nt (read-once stream; don't evict weights in L2)
//   * seq0 per-step stores: nt (no write-allocate churn of the weight set)
// Weight chunk loads stay cacheable -> 512 KB/XCD stays L2-resident
// (round-7 FETCH=68MB showed streaming traffic was evicting them; the
// resulting L2 misses serialized in the depth-1 load->MFMA chain).
// ---------------------------------------------------------------------------
#define LDW(BUF, CW)                                                                      \
  {                                                                                       \
    const __hip_bfloat16* p_ =                                                            \
        Wd + ((size_t)(((CW) >> 2) * 256 + w * 64 + ((CW)&3) * 16 + l16)) * 256 +         \
        quad * 8;                                                                         \
    _Pragma("unroll") for (int kc_ = 0; kc_ < 8; ++kc_) BUF[kc_] =                        \
        *(const short8*)(p_ + kc_ * 32);                                                  \
  }
#define MMW(BUF, CW)                                                                      \
  {                                                                                       \
    _Pragma("unroll") for (int kc_ = 0; kc_ < 8; ++kc_) acc[(CW) >> 2][(CW)&3] =          \
        __builtin_amdgcn_mfma_f32_16x16x32_bf16(areg[kc_], BUF[kc_],                      \
                                                acc[(CW) >> 2][(CW)&3], 0, 0, 0);         \
  }

template <bool WRITE_SEQ>
__launch_bounds__(256, 1) __global__
void k_lstm_fast(const __hip_bfloat16* __restrict__ WhT,   // [2][1024][256] this layer
                 const __hip_bfloat16* __restrict__ xproj,  // [2][Tc][4][8][256][8] bf16
                 const float* __restrict__ biasL,           // [2][1024] this layer
                 const int* __restrict__ lengths,
                 float* __restrict__ cstate, float* __restrict__ hstate,  // [2][64][256]
                 __hip_bfloat16* __restrict__ seq0,         // [T][64][512]
                 const int s0, const int Tc) {
  const int d = blockIdx.x >> 2;
  const int beta = blockIdx.x & 3;
  const int tid = threadIdx.x;
  const int w = tid >> 6, L = tid & 63, quad = L >> 4, l16 = L & 15;

  __shared__ __hip_bfloat16 h_lds[16][264];

  const __hip_bfloat16* __restrict__ Wd = WhT + (size_t)d * (1024 * 256);

  float bz[4][4];
#pragma unroll
  for (int g = 0; g < 4; ++g)
#pragma unroll
    for (int u4 = 0; u4 < 4; ++u4)
      bz[g][u4] = biasL[d * 1024 + g * 256 + w * 64 + u4 * 16 + l16];

  int len_b[4];
#pragma unroll
  for (int r = 0; r < 4; ++r) len_b[r] = lengths[beta * 16 + quad * 4 + r];

  float c_reg[16], h_reg[16];
#pragma unroll
  for (int u4 = 0; u4 < 4; ++u4)
#pragma unroll
    for (int r = 0; r < 4; ++r) {
      const int idx = u4 * 4 + r;
      const int b = beta * 16 + quad * 4 + r;
      const int u = w * 64 + u4 * 16 + l16;
      if (s0 == 0) {
        c_reg[idx] = 0.0f;
        h_reg[idx] = 0.0f;
      } else {
        c_reg[idx] = cstate[((size_t)(d * 64 + b) << 8) + u];
        h_reg[idx] = hstate[((size_t)(d * 64 + b) << 8) + u];
      }
    }
#pragma unroll
  for (int u4 = 0; u4 < 4; ++u4)
#pragma unroll
    for (int r = 0; r < 4; ++r)
      h_lds[quad * 4 + r][w * 64 + u4 * 16 + l16] = __float2bfloat16(h_reg[u4 * 4 + r]);
  __syncthreads();

  // per-(d,beta,tid) xproj stream base (8 x 16B chunks per step)
  const __hip_bfloat16* __restrict__ xqb =
      xproj + (size_t)d * Tc * 65536 + (size_t)beta * 16384 + (size_t)tid * 8;

  for (int sl = 0; sl < Tc; ++sl) {
    const int s = s0 + sl;
    const int t = d ? (Tn - 1 - s) : s;
    const int tl = d ? (Tc - 1 - sl) : sl;

    // 1. issue xproj loads, NON-TEMPORAL (consumed in gate phase -> hidden
    //    under chunk loop; nt keeps the stream out of L2)
    short8 xv[8];
    {
      const __hip_bfloat16* __restrict__ src = xqb + (size_t)tl * 65536;
#pragma unroll
      for (int ch = 0; ch < 8; ++ch)
        xv[ch] = __builtin_nontemporal_load((const short8*)(src + ch * 2048));
    }

    // 2. A-fragments from local h (reused across all 16 weight chunks)
    short8 areg[8];
#pragma unroll
    for (int kc = 0; kc < 8; ++kc)
      areg[kc] = *(const short8*)&h_lds[l16][kc * 32 + quad * 8];

    // 3. acc = bias; stream weights (16 chunks, reg double-buffer) + MFMA
    f32x4 acc[4][4];
#pragma unroll
    for (int g = 0; g < 4; ++g)
#pragma unroll
      for (int u4 = 0; u4 < 4; ++u4) {
        acc[g][u4][0] = bz[g][u4]; acc[g][u4][1] = bz[g][u4];
        acc[g][u4][2] = bz[g][u4]; acc[g][u4][3] = bz[g][u4];
      }

    short8 wfA[8], wfB[8];
    LDW(wfA, 0)
    LDW(wfB, 1) MMW(wfA, 0)
    LDW(wfA, 2) MMW(wfB, 1)
    LDW(wfB, 3) MMW(wfA, 2)
    LDW(wfA, 4) MMW(wfB, 3)
    LDW(wfB, 5) MMW(wfA, 4)
    LDW(wfA, 6) MMW(wfB, 5)
    LDW(wfB, 7) MMW(wfA, 6)
    LDW(wfA, 8) MMW(wfB, 7)
    LDW(wfB, 9) MMW(wfA, 8)
    LDW(wfA, 10) MMW(wfB, 9)
    LDW(wfB, 11) MMW(wfA, 10)
    LDW(wfA, 12) MMW(wfB, 11)
    LDW(wfB, 13) MMW(wfA, 12)
    LDW(wfA, 14) MMW(wfB, 13)
    LDW(wfB, 15) MMW(wfA, 14)
    MMW(wfB, 15)

    // 4. gates: z = acc + xproj; update state
    __hip_bfloat16 hbf[16];
#pragma unroll
    for (int u4 = 0; u4 < 4; ++u4)
#pragma unroll
      for (int r = 0; r < 4; ++r) {
        const int idx = u4 * 4 + r;
        const int e = (u4 & 1) * 4 + r;
        const int cbase = (u4 >> 1);
        const short svf = xv[0 * 2 + cbase][e];
        const short svi = xv[1 * 2 + cbase][e];
        const short svg = xv[2 * 2 + cbase][e];
        const short svo = xv[3 * 2 + cbase][e];
        const float zf = acc[0][u4][r] + __bfloat162float(*(const __hip_bfloat16*)&svf);
        const float zi = acc[1][u4][r] + __bfloat162float(*(const __hip_bfloat16*)&svi);
        const float zg = acc[2][u4][r] + __bfloat162float(*(const __hip_bfloat16*)&svg);
        const float zo = acc[3][u4][r] + __bfloat162float(*(const __hip_bfloat16*)&svo);
        const float fg = sigmf(zf);
        const float ig = sigmf(zi);
        const float gg = tanh_fast(zg);
        const float og = sigmf(zo);
        const float cn = fg * c_reg[idx] + ig * gg;
        const float hn = og * tanh_fast(cn);
        if (t < len_b[r]) {
          c_reg[idx] = cn;
          h_reg[idx] = hn;
        }
        hbf[idx] = __float2bfloat16(h_reg[idx]);
      }

    __syncthreads();  // all waves done reading h_lds (areg) before overwrite

#pragma unroll
    for (int u4 = 0; u4 < 4; ++u4)
#pragma unroll
      for (int r = 0; r < 4; ++r)
        h_lds[quad * 4 + r][w * 64 + u4 * 16 + l16] = hbf[u4 * 4 + r];

    if (WRITE_SEQ) {
#pragma unroll
      for (int u4 = 0; u4 < 4; ++u4)
#pragma unroll
        for (int r = 0; r < 4; ++r) {
          const int b = beta * 16 + quad * 4 + r;
          __builtin_nontemporal_store(
              *(const short*)&hbf[u4 * 4 + r],
              (short*)(seq0 + ((size_t)t * 64 + b) * 512 + d * 256 + w * 64 + u4 * 16 +
                       l16));
        }
    }

    __syncthreads();  // h_lds ready for next step
  }

#pragma unroll
  for (int u4 = 0; u4 < 4; ++u4)
#pragma unroll
    for (int r = 0; r < 4; ++r) {
      const int idx = u4 * 4 + r;
      const int b = beta * 16 + quad * 4 + r;
      const int u = w * 64 + u4 * 16 + l16;
      cstate[((size_t)(d * 64 + b) << 8) + u] = c_reg[idx];
      hstate[((size_t)(d * 64 + b) << 8) + u] = h_reg[idx];
    }
}
#undef LDW
#undef MMW

// ===========================================================================
// SLOW FALLBACK PATH (round-2 passing version, used when ws is too small)
// ===========================================================================
template <typename TW, int XK, bool WRITE_SEQ>
__device__ __forceinline__ void lstm_body(const int* __restrict__ x, const TW* __restrict__ E,
                                          const __hip_bfloat16* __restrict__ seq_in,
                                          const TW* __restrict__ W, const TW* __restrict__ bias,
                                          const int len, const int b, const int dir,
                                          __hip_bfloat16* __restrict__ seq_out,
                                          float* __restrict__ hfin) {
  const int j = threadIdx.x;
  __shared__ float h[Hn];
  __shared__ float xb[XK];
  float hj = 0.0f, cj = 0.0f;
  h[j] = 0.0f;
  const float bfj = ldf(bias, j);
  const float bij = ldf(bias, Hn + j);
  const float bgj = ldf(bias, 2 * Hn + j);
  const float boj = ldf(bias, 3 * Hn + j);
  __syncthreads();
  for (int s = 0; s < Tn; ++s) {
    const int t = dir ? (Tn - 1 - s) : s;
    const bool active = (t < len);
    if (active) {
      if constexpr (XK == Dn) {
        const int tok = x[b * Tn + t];
        xb[j] = ldf(E, (long)tok * Dn + j);
      } else {
        const long base = ((long)(b * Tn + t)) * (2 * Hn);
        xb[j] = __bfloat162float(seq_in[base + j]);
        xb[j + Hn] = __bfloat162float(seq_in[base + j + Hn]);
      }
      __syncthreads();
      float af = bfj, ai = bij, ag = bgj, ao = boj;
#pragma unroll 4
      for (int k = 0; k < Hn; ++k) {
        const float hk = h[k];
        const long r = (long)k * (4 * Hn);
        af += hk * ldf(W, r + j);
        ai += hk * ldf(W, r + Hn + j);
        ag += hk * ldf(W, r + 2 * Hn + j);
        ao += hk * ldf(W, r + 3 * Hn + j);
      }
#pragma unroll 4
      for (int k = 0; k < XK; ++k) {
        const float xk = xb[k];
        const long r = (long)(Hn + k) * (4 * Hn);
        af += xk * ldf(W, r + j);
        ai += xk * ldf(W, r + Hn + j);
        ag += xk * ldf(W, r + 2 * Hn + j);
        ao += xk * ldf(W, r + 3 * Hn + j);
      }
      const float fg = 1.0f / (1.0f + expf(-af));
      const float ig = 1.0f / (1.0f + expf(-ai));
      const float gg = tanhf(ag);
      const float og = 1.0f / (1.0f + expf(-ao));
      const float cn = fg * cj + ig * gg;
      const float hn = og * tanhf(cn);
      __syncthreads();
      hj = hn;
      cj = cn;
      h[j] = hn;
      __syncthreads();
    }
    if constexpr (WRITE_SEQ) {
      seq_out[((long)(b * Tn + t)) * (2 * Hn) + dir * Hn + j] = __float2bfloat16(hj);
    }
  }
  if constexpr (!WRITE_SEQ) hfin[(dir * Bn + b) * Hn + j] = hj;
}

template <int XK, bool WRITE_SEQ>
__global__ void k_lstm(const int* __restrict__ x, const void* __restrict__ E,
                       const __hip_bfloat16* __restrict__ seq_in, const void* __restrict__ Wf,
                       const void* __restrict__ bf, const void* __restrict__ Wb,
                       const void* __restrict__ bb, const int* __restrict__ lengths,
                       const int* __restrict__ flag, __hip_bfloat16* __restrict__ seq_out,
                       float* __restrict__ hfin) {
  const int b = blockIdx.x & (Bn - 1);
  const int dir = blockIdx.x >> 6;
  const int len = lengths[b];
  const void* W = dir ? Wb : Wf;
  const void* bias = dir ? bb : bf;
  if (flag[0]) {
    lstm_body<float, XK, WRITE_SEQ>(x, (const float*)E, seq_in, (const float*)W,
                                    (const float*)bias, len, b, dir, seq_out, hfin);
  } else {
    lstm_body<__hip_bfloat16, XK, WRITE_SEQ>(x, (const __hip_bfloat16*)E, seq_in,
                                             (const __hip_bfloat16*)W, (const __hip_bfloat16*)bias,
                                             len, b, dir, seq_out, hfin);
  }
}

// ---------------------------------------------------------------------------
template <typename TW>
__device__ __forceinline__ void fc_body(const float* __restrict__ hfin, const TW* __restrict__ Wfc,
                                        const TW* __restrict__ bfc, TW* __restrict__ out) {
  const int idx = threadIdx.x;
  const int b = idx >> 1;
  const int cc = idx & 1;
  float acc = ldf(bfc, cc);
  for (int k = 0; k < Hn; ++k) acc += hfin[(0 * Bn + b) * Hn + k] * ldf(Wfc, k * 2 + cc);
  for (int k = 0; k < Hn; ++k) acc += hfin[(1 * Bn + b) * Hn + k] * ldf(Wfc, (Hn + k) * 2 + cc);
  if constexpr (sizeof(TW) == 2) {
    out[b * 2 + cc] = __float2bfloat16(acc);
  } else {
    out[b * 2 + cc] = acc;
  }
}

__global__ void k_fc(const float* __restrict__ hfin, const void* __restrict__ Wfc,
                     const void* __restrict__ bfc, const int* __restrict__ flag,
                     void* __restrict__ out) {
  if (flag[0]) {
    fc_body<float>(hfin, (const float*)Wfc, (const float*)bfc, (float*)out);
  } else {
    fc_body<__hip_bfloat16>(hfin, (const __hip_bfloat16*)Wfc, (const __hip_bfloat16*)bfc,
                            (__hip_bfloat16*)out);
  }
}

// ---------------------------------------------------------------------------
extern "C" void kernel_launch(void* const* d_in, const int* in_sizes, int n_in,
                              void* d_out, int out_size, void* d_ws, size_t ws_size,
                              hipStream_t stream) {
  const int* x = (const int*)d_in[0];
  const void* E = d_in[1];
  const void* Wf0 = d_in[2];
  const void* bf0 = d_in[3];
  const void* Wb0 = d_in[4];
  const void* bb0 = d_in[5];
  const void* Wf1 = d_in[6];
  const void* bf1 = d_in[7];
  const void* Wb1 = d_in[8];
  const void* bb1 = d_in[9];
  const void* Wfc = d_in[10];
  const void* bfc = d_in[11];

  char* ws = (char*)d_ws;
  int* flag = (int*)ws;             // @0
  int* lengths = (int*)(ws + 256);

  const size_t MB = 1ull << 20;
  const size_t KB = 1024;

  k_detect<<<1, 256, 0, stream>>>((const unsigned short*)E, flag);
  k_lengths<<<Bn, 256, 0, stream>>>(x, lengths);

  // fixed 73 MB (weights/state/seq0) + one bf16 xproj slot Tc*256KB (reused L0/L1)
  int Tc = 0;
  {
    const size_t fixed = 73 * MB;
    const int cands[7] = {1024, 512, 256, 128, 64, 32, 16};
    for (int i = 0; i < 7; ++i)
      if (fixed + (size_t)cands[i] * 256 * KB <= ws_size) { Tc = cands[i]; break; }
  }

  if (Tc > 0) {
    float* biasbuf = (float*)(ws + 4096);                    // 16 KB
    __hip_bfloat16* whT = (__hip_bfloat16*)(ws + 1 * MB);    // [4][1024][256] = 2 MB
    __hip_bfloat16* wxT0 = (__hip_bfloat16*)(ws + 3 * MB);   // [2][1024][256] = 1 MB
    __hip_bfloat16* wxT1 = (__hip_bfloat16*)(ws + 4 * MB);   // [2][1024][512] = 2 MB
    float* cstate0 = (float*)(ws + 7 * MB);                  // 128 KB
    float* hstate0 = (float*)(ws + 7 * MB + 128 * KB);       // 128 KB
    float* cstate1 = (float*)(ws + 7 * MB + 256 * KB);       // 128 KB
    float* hstate1 = (float*)(ws + 7 * MB + 384 * KB);       // 128 KB
    __hip_bfloat16* seq0 = (__hip_bfloat16*)(ws + 8 * MB);   // [1024][64][512] = 64 MB
    __hip_bfloat16* xsl = (__hip_bfloat16*)(ws + 73 * MB);   // [2][Tc][4][8][256][8] bf16

    k_prep_small<<<1, 256, 0, stream>>>(bf0, bb0, bf1, bb1, flag, biasbuf);
    k_prepw<<<dim3(12, 16, 4), 256, 0, stream>>>(Wf0, Wb0, Wf1, Wb1, flag, whT, wxT0, wxT1);

    const int P = Tn / Tc;
    const int Mrows = Tc * 64;
    const int ntiles = (Mrows / 128) * 16;
    // layer 0
    for (int p = 0; p < P; ++p) {
      const int s0 = p * Tc;
      const int t0f = s0, t0b = Tn - s0 - Tc;
      k_xproj3<256, true><<<ntiles, 256, 0, stream>>>(x, E, flag, nullptr, nullptr, wxT0, xsl,
                                                      Mrows, t0f, t0b);
      k_lstm_fast<true><<<8, 256, 0, stream>>>(whT, xsl, biasbuf, lengths, cstate0, hstate0,
                                               seq0, s0, Tc);
    }
    // layer 1
    for (int p = 0; p < P; ++p) {
      const int s0 = p * Tc;
      const int t0f = s0, t0b = Tn - s0 - Tc;
      k_xproj3<512, false><<<ntiles, 256, 0, stream>>>(
          x, E, flag, seq0 + (size_t)t0f * 64 * 512, seq0 + (size_t)t0b * 64 * 512, wxT1, xsl,
          Mrows, 0, 0);
      k_lstm_fast<false><<<8, 256, 0, stream>>>(whT + 2 * 1024 * 256, xsl, biasbuf + 2048,
                                                lengths, cstate1, hstate1, nullptr, s0, Tc);
    }
    k_fc<<<1, 128, 0, stream>>>(hstate1, Wfc, bfc, flag, d_out);
  } else {
    // slow fallback (round-2 passing path)
    __hip_bfloat16* seq0 = (__hip_bfloat16*)(ws + 64 * 1024);
    const size_t seq0_bytes = (size_t)Bn * Tn * 2 * Hn * sizeof(__hip_bfloat16);
    float* hfin = (float*)(ws + 64 * 1024 + seq0_bytes);
    k_lstm<Dn, true><<<2 * Bn, 256, 0, stream>>>(x, E, nullptr, Wf0, bf0, Wb0, bb0, lengths, flag,
                                                 seq0, nullptr);
    k_lstm<2 * Hn, false><<<2 * Bn, 256, 0, stream>>>(x, E, seq0, Wf1, bf1, Wb1, bb1, lengths,
                                                      flag, nullptr, hfin);
    k_fc<<<1, 128, 0, stream>>>(hfin, Wfc, bfc, flag, d_out);
  }
}

// Round 9
// 15114.671 us; speedup vs baseline: 1.6103x; 1.6103x over previous
//
#include <hip/hip_runtime.h>
#include <hip/hip_bf16.h>
#include <math.h>

// Problem constants: V=32000, D=256, H=256, L=2, C=2, B=64, T=1024, PAD=0
namespace {
constexpr int Bn = 64;
constexpr int Tn = 1024;
constexpr int Dn = 256;
constexpr int Hn = 256;
}

typedef __attribute__((ext_vector_type(8))) short short8;
typedef __attribute__((ext_vector_type(4))) float f32x4;

template <typename T>
__device__ __forceinline__ float ldf(const T* p, long i);
template <>
__device__ __forceinline__ float ldf<float>(const float* p, long i) { return p[i]; }
template <>
__device__ __forceinline__ float ldf<__hip_bfloat16>(const __hip_bfloat16* p, long i) {
  return __bfloat162float(p[i]);
}

__device__ __forceinline__ float sigmf(float x) { return 1.0f / (1.0f + __expf(-x)); }
__device__ __forceinline__ float tanh_fast(float x) {
  return 1.0f - 2.0f / (__expf(2.0f * x) + 1.0f);
}

// ---------------------------------------------------------------------------
// Dtype detector (validated round 2: flag=1 -> f32 inputs).
// ---------------------------------------------------------------------------
__global__ void k_detect(const unsigned short* __restrict__ e, int* __restrict__ flag) {
  __shared__ int sbuf[256];
  int bad = 0;
  for (int i = threadIdx.x; i < 4096; i += 256) {
    const unsigned short v = e[i];
    const int ex = (v >> 7) & 0xFF;
    bad += (ex >= 137) ? 1 : 0;
  }
  sbuf[threadIdx.x] = bad;
  __syncthreads();
  for (int s = 128; s > 0; s >>= 1) {
    if (threadIdx.x < s) sbuf[threadIdx.x] += sbuf[threadIdx.x + s];
    __syncthreads();
  }
  if (threadIdx.x == 0) flag[0] = (sbuf[0] > 64) ? 1 : 0;
}

__global__ void k_lengths(const int* __restrict__ x, int* __restrict__ len) {
  const int b = blockIdx.x;
  int cnt = 0;
  for (int t = threadIdx.x; t < Tn; t += blockDim.x) cnt += (x[b * Tn + t] != 0) ? 1 : 0;
  __shared__ int sbuf[256];
  sbuf[threadIdx.x] = cnt;
  __syncthreads();
  for (int s = 128; s > 0; s >>= 1) {
    if (threadIdx.x < s) sbuf[threadIdx.x] += sbuf[threadIdx.x + s];
    __syncthreads();
  }
  if (threadIdx.x == 0) len[b] = sbuf[0];
}

// ===========================================================================
// FAST PATH
// ===========================================================================

// biases -> f32 [4][1024] (order: f0,b0,f1,b1).
__global__ void k_prep_small(const void* b0f, const void* b0b, const void* b1f, const void* b1b,
                             const int* __restrict__ flag, float* __restrict__ biasbuf) {
  const int tid = threadIdx.x;
  const bool isf32 = flag[0] != 0;
  for (int idx = tid; idx < 4096; idx += 256) {
    const int j = idx >> 10, col = idx & 1023;
    const void* src = (j == 0) ? b0f : (j == 1) ? b0b : (j == 2) ? b1f : b1b;
    biasbuf[idx] = isf32 ? ((const float*)src)[col]
                         : __bfloat162float(((const __hip_bfloat16*)src)[col]);
  }
}

// Transpose+convert W[(H+XK) x 1024] -> WhT bf16 [1024][256], WxT bf16 [1024][XK].
__global__ void k_prepw(const void* W0, const void* W1, const void* W2, const void* W3,
                        const int* __restrict__ flag, __hip_bfloat16* __restrict__ whT,
                        __hip_bfloat16* __restrict__ wxT0, __hip_bfloat16* __restrict__ wxT1) {
  const int j = blockIdx.z;
  const int rows = (j < 2) ? 512 : 768;
  const int bx = blockIdx.x;
  if (bx * 64 >= rows) return;
  const int by = blockIdx.y;
  const void* W = (j == 0) ? W0 : (j == 1) ? W1 : (j == 2) ? W2 : W3;
  const bool isf32 = flag[0] != 0;
  __shared__ float tile[64][65];
  const int tid = threadIdx.x;
  const int c = tid & 63, r4 = tid >> 6;
#pragma unroll
  for (int rep = 0; rep < 16; ++rep) {
    const int rr = r4 * 16 + rep;
    const size_t idx = (size_t)(bx * 64 + rr) * 1024 + by * 64 + c;
    tile[rr][c] = isf32 ? ((const float*)W)[idx]
                        : __bfloat162float(((const __hip_bfloat16*)W)[idx]);
  }
  __syncthreads();
  const int kk = tid & 63;
#pragma unroll
  for (int rep = 0; rep < 16; ++rep) {
    const int a = r4 * 16 + rep;
    const int n = by * 64 + a;
    const int k = bx * 64 + kk;
    const __hip_bfloat16 v = __float2bfloat16(tile[kk][a]);
    if (k < 256) {
      whT[(size_t)j * (1024 * 256) + (size_t)n * 256 + k] = v;
    } else {
      const int k2 = k - 256;
      if (j < 2)
        wxT0[(size_t)j * (1024 * 256) + (size_t)n * 256 + k2] = v;
      else
        wxT1[(size_t)(j - 2) * (1024 * 512) + (size_t)n * 512 + k2] = v;
    }
  }
}

// ---------------------------------------------------------------------------
// xproj GEMM v4 (validated rounds 2-6): 128x128 tile/block, B in LDS, A from
// global/gather; OUTPUT in the consumer-native layout of k_lstm_fast:
//   xp[d][tl][q 0..3][jv 0..7][tid 0..255][8 bf16]   (per (d,tl): 128 KB)
// Producer mapping (verified): tl = bx*2+(w>>1); jv = (by>>1)*2+(w&1);
//   q = (by&1)*2+(nt>>2); tid_c = (nt&3)*64+quad*16+l16; elem = mt2*4+r.
// ---------------------------------------------------------------------------
template <int K, bool GATHER>
__launch_bounds__(256, 2)
__global__ void k_xproj3(const int* __restrict__ x, const void* __restrict__ E,
                         const int* __restrict__ flag, const __hip_bfloat16* __restrict__ Af,
                         const __hip_bfloat16* __restrict__ Ab,
                         const __hip_bfloat16* __restrict__ WT,  // [2][1024][K]
                         __hip_bfloat16* __restrict__ xp,        // [2][Tc][4][8][256][8]
                         const int Mrows, const int t0f, const int t0b) {
  constexpr int KC = 256;
  __shared__ __hip_bfloat16 Btile[128][KC + 8];
  const int tix = blockIdx.x;
  const int by = tix & 7;
  const int dz = (tix >> 3) & 1;
  const int bx = tix >> 4;
  const int tid = threadIdx.x, w = tid >> 6, L = tid & 63, quad = L >> 4, l16 = L & 15;
  const __hip_bfloat16* __restrict__ WTd = WT + (size_t)dz * (1024 * K);
  __hip_bfloat16* __restrict__ o = xp + (size_t)dz * Mrows * 1024;

  f32x4 acc[2][8];
#pragma unroll
  for (int mt = 0; mt < 2; ++mt)
#pragma unroll
    for (int nt = 0; nt < 8; ++nt) {
      acc[mt][nt][0] = 0.f; acc[mt][nt][1] = 0.f; acc[mt][nt][2] = 0.f; acc[mt][nt][3] = 0.f;
    }

  const int row0 = bx * 128 + w * 32 + l16;  // a0 row; a1 = row0+16
  const __hip_bfloat16* arow0b = nullptr;
  const __hip_bfloat16* arow1b = nullptr;
  const float* arow0f = nullptr;
  const float* arow1f = nullptr;
  bool isf32 = false;
  if constexpr (GATHER) {
    isf32 = flag[0] != 0;
    const int t0 = (dz ? t0b : t0f) + (row0 >> 6), b0 = row0 & 63;
    const int r1 = row0 + 16;
    const int t1 = (dz ? t0b : t0f) + (r1 >> 6), b1 = r1 & 63;
    const int tok0 = x[b0 * Tn + t0];
    const int tok1 = x[b1 * Tn + t1];
    if (isf32) {
      arow0f = (const float*)E + (size_t)tok0 * Dn;
      arow1f = (const float*)E + (size_t)tok1 * Dn;
    } else {
      arow0b = (const __hip_bfloat16*)E + (size_t)tok0 * Dn;
      arow1b = (const __hip_bfloat16*)E + (size_t)tok1 * Dn;
    }
  } else {
    const __hip_bfloat16* A = dz ? Ab : Af;
    arow0b = A + (size_t)row0 * K;
    arow1b = A + (size_t)(row0 + 16) * K;
  }

  for (int ch = 0; ch < K / KC; ++ch) {
    if (ch) __syncthreads();
    // stage B chunk: 128 cols x 256 shorts
#pragma unroll
    for (int it = 0; it < 16; ++it) {
      const int idx = it * 256 + tid;
      const int col = idx >> 5, seg = idx & 31;
      *(short8*)&Btile[col][seg * 8] =
          *(const short8*)(WTd + (size_t)(by * 128 + col) * K + ch * KC + seg * 8);
    }
    __syncthreads();

#pragma unroll
    for (int kc = 0; kc < 8; ++kc) {
      short8 a0, a1;
      if constexpr (GATHER) {
        if (isf32) {
#pragma unroll
          for (int jj = 0; jj < 8; ++jj) {
            __hip_bfloat16 h0 = __float2bfloat16(arow0f[kc * 32 + quad * 8 + jj]);
            __hip_bfloat16 h1 = __float2bfloat16(arow1f[kc * 32 + quad * 8 + jj]);
            a0[jj] = *(const short*)&h0;
            a1[jj] = *(const short*)&h1;
          }
        } else {
          a0 = *(const short8*)(arow0b + kc * 32 + quad * 8);
          a1 = *(const short8*)(arow1b + kc * 32 + quad * 8);
        }
      } else {
        a0 = *(const short8*)(arow0b + ch * KC + kc * 32 + quad * 8);
        a1 = *(const short8*)(arow1b + ch * KC + kc * 32 + quad * 8);
      }
#pragma unroll
      for (int nt = 0; nt < 8; ++nt) {
        const short8 b = *(const short8*)&Btile[nt * 16 + l16][kc * 32 + quad * 8];
        acc[0][nt] = __builtin_amdgcn_mfma_f32_16x16x32_bf16(a0, b, acc[0][nt], 0, 0, 0);
        acc[1][nt] = __builtin_amdgcn_mfma_f32_16x16x32_bf16(a1, b, acc[1][nt], 0, 0, 0);
      }
    }
  }

  // --- epilogue: consumer-native layout, fully coalesced 16B stores ---
  {
    const int tl = bx * 2 + (w >> 1);
    const int jv = (by >> 1) * 2 + (w & 1);
    const int qbase = (by & 1) << 1;
    __hip_bfloat16* __restrict__ ob = o + (size_t)tl * 65536 + (size_t)jv * 2048;
#pragma unroll
    for (int nt = 0; nt < 8; ++nt) {
      const int q_ = qbase + (nt >> 2);
      const int tid_c = (nt & 3) * 64 + quad * 16 + l16;
      short8 sv;
#pragma unroll
      for (int r = 0; r < 4; ++r) {
        __hip_bfloat16 h0 = __float2bfloat16(acc[0][nt][r]);
        __hip_bfloat16 h1 = __float2bfloat16(acc[1][nt][r]);
        sv[r] = *(const short*)&h0;
        sv[4 + r] = *(const short*)&h1;
      }
      *(short8*)(ob + (size_t)q_ * 16384 + tid_c * 8) = sv;
    }
  }
}

// ---------------------------------------------------------------------------
// Phased recurrent layer v10: EXACT round-6 v8 body (256 thr, hint flags +
// validated tagged-payload sweep, steady 3745 us) with XCD-AWARE PLACEMENT:
// launch 64 blocks; under the hardware's round-robin block->XCD dispatch,
// worker (d, q) is placed at blockIdx = d + 8*q so all 4 q-blocks of
// direction d land on XCD d. The mailbox exchange then stays within ONE
// XCD's L2 instead of crossing MALL (the ~6 us/step visibility latency
// rounds 3-6 proved irreducible from the consumer side). The other 56
// blocks exit immediately. Placement is a heuristic ONLY -- protocol
// correctness (tags) is placement-agnostic, and 64 blocks <= 256 CUs so
// all workers are co-resident at launch.
// ---------------------------------------------------------------------------
template <bool WRITE_SEQ>
__launch_bounds__(256, 1) __global__
void k_lstm_fast(const __hip_bfloat16* __restrict__ WhT,   // [2][1024][256] this layer
                 const __hip_bfloat16* __restrict__ xproj,  // [2][Tc][4][8][256][8] bf16
                 const float* __restrict__ biasL,           // [2][1024] this layer
                 const int* __restrict__ lengths,
                 unsigned* __restrict__ hgs,     // [2 d][2 par][4 q][64 b][64 u] u32
                 unsigned* __restrict__ hflags,  // [2 d][2 par][4 q][4 w] u32 hint flags
                 float* __restrict__ cstate, float* __restrict__ hstate,  // [2][64][256]
                 __hip_bfloat16* __restrict__ seq0,         // [T][64][512]
                 const int s0, const int Tc) {
  // XCD-aware remap: worker iff (bid&7)<2 && (bid>>3)<4; d = bid&7, q = bid>>3.
  const int xcd = blockIdx.x & 7;
  const int kq = blockIdx.x >> 3;
  if (xcd >= 2 || kq >= 4) return;
  const int d = xcd;
  const int q = kq;
  const int tid = threadIdx.x;
  const int w = tid >> 6, L = tid & 63, quad = L >> 4, l16 = L & 15;
  const int u = q * 64 + w * 16 + l16;

  __shared__ __hip_bfloat16 h_lds[64][272];
  for (int idx = tid; idx < 64 * 272; idx += 256) (&h_lds[0][0])[idx] = __float2bfloat16(0.0f);

  const __hip_bfloat16* __restrict__ Wd = WhT + (size_t)d * (1024 * 256);
  short8 wfrag[4][8];
#pragma unroll
  for (int g = 0; g < 4; ++g)
#pragma unroll
    for (int kc = 0; kc < 8; ++kc)
      wfrag[g][kc] = *(const short8*)(Wd + (size_t)(g * 256 + u) * 256 + kc * 32 + quad * 8);

  float bz[4];
#pragma unroll
  for (int g = 0; g < 4; ++g) bz[g] = biasL[d * 1024 + g * 256 + u];

  float c_reg[16], h_reg[16];
  int len_b[16];
#pragma unroll
  for (int mt = 0; mt < 4; ++mt)
#pragma unroll
    for (int r = 0; r < 4; ++r) {
      const int idx = mt * 4 + r;
      const int b = mt * 16 + quad * 4 + r;
      len_b[idx] = lengths[b];
      if (s0 == 0) {
        c_reg[idx] = 0.0f;
        h_reg[idx] = 0.0f;
      } else {
        c_reg[idx] = cstate[((size_t)(d * 64 + b) << 8) + u];
        h_reg[idx] = hstate[((size_t)(d * 64 + b) << 8) + u];
      }
    }
  __syncthreads();
#pragma unroll
  for (int mt = 0; mt < 4; ++mt)
#pragma unroll
    for (int r = 0; r < 4; ++r)
      h_lds[mt * 16 + quad * 4 + r][u] = __float2bfloat16(h_reg[mt * 4 + r]);
  __syncthreads();

  // base of this (d, q, tid)'s xproj stream
  const __hip_bfloat16* __restrict__ xq =
      xproj + (size_t)d * Tc * 65536 + (size_t)q * 16384 + (size_t)tid * 8;

  for (int sl = 0; sl < Tc; ++sl) {
    const int s = s0 + sl;
    const int t = d ? (Tn - 1 - s) : s;
    const int tl = d ? (Tc - 1 - sl) : sl;

    // 1. issue coalesced xproj loads (consumed after the exchange -> latency
    //    hides under the spin; only 32 VGPRs live across it)
    short8 xv[8];
    {
      const __hip_bfloat16* __restrict__ src = xq + (size_t)tl * 65536;
#pragma unroll
      for (int jv = 0; jv < 8; ++jv) xv[jv] = *(const short8*)(src + jv * 2048);
    }

    // 2. exchange: hint-flag pre-spin, then the validated tagged sweep
    if (s > 0) {
      if (w != q) {
        const unsigned exp = (unsigned)s;
        // 2a. cheap hint spin: 4x4B uniform loads per retry
        {
          const unsigned* __restrict__ f4 =
              hflags + (((d * 2 + ((s - 1) & 1)) * 4 + w) * 4);
          for (;;) {
            const unsigned f0 =
                __hip_atomic_load(f4 + 0, __ATOMIC_RELAXED, __HIP_MEMORY_SCOPE_AGENT);
            const unsigned f1 =
                __hip_atomic_load(f4 + 1, __ATOMIC_RELAXED, __HIP_MEMORY_SCOPE_AGENT);
            const unsigned f2 =
                __hip_atomic_load(f4 + 2, __ATOMIC_RELAXED, __HIP_MEMORY_SCOPE_AGENT);
            const unsigned f3 =
                __hip_atomic_load(f4 + 3, __ATOMIC_RELAXED, __HIP_MEMORY_SCOPE_AGENT);
            if (f0 >= exp && f1 >= exp && f2 >= exp && f3 >= exp) break;
            __builtin_amdgcn_s_sleep(1);
          }
        }
        // 2b. validated tagged-payload sweep (normally single pass now)
        const unsigned long long* __restrict__ src64 =
            (const unsigned long long*)(hgs + ((((size_t)d * 2 + ((s - 1) & 1)) * 4 + w) << 12));
        unsigned long long v[32];
        unsigned pend = 0xFFFFFFFFu;
        int tries = 0;
        do {
          if (tries++) __builtin_amdgcn_s_sleep(1);
#pragma unroll
          for (int i = 0; i < 32; ++i)
            if (pend & (1u << i))
              v[i] = __hip_atomic_load(src64 + i * 64 + L, __ATOMIC_RELAXED,
                                       __HIP_MEMORY_SCOPE_AGENT);
#pragma unroll
          for (int i = 0; i < 32; ++i)
            if (pend & (1u << i)) {
              const unsigned lo = (unsigned)v[i], hi = (unsigned)(v[i] >> 32);
              if ((lo >> 16) == exp && (hi >> 16) == exp) pend &= ~(1u << i);
            }
        } while (pend);
#pragma unroll
        for (int i = 0; i < 32; ++i) {
          const int j = i * 64 + L;
          const unsigned lo = (unsigned)v[i], hi = (unsigned)(v[i] >> 32);
          const unsigned packed = (lo & 0xFFFFu) | (hi << 16);
          *(unsigned*)&h_lds[j >> 5][w * 64 + (j & 31) * 2] = packed;
        }
      }
      __syncthreads();
    }

    // 3. unpack xproj + f32 bias -> acc
    f32x4 acc[4][4];
#pragma unroll
    for (int mt = 0; mt < 4; ++mt)
#pragma unroll
      for (int g = 0; g < 4; ++g) {
        const short8 v = xv[g * 2 + (mt >> 1)];
#pragma unroll
        for (int r = 0; r < 4; ++r) {
          const short sv = v[(mt & 1) * 4 + r];
          acc[mt][g][r] = __bfloat162float(*(const __hip_bfloat16*)&sv) + bz[g];
        }
      }

    // 4. z += h @ Wh
#pragma unroll
    for (int kc = 0; kc < 8; ++kc) {
#pragma unroll
      for (int mt = 0; mt < 4; ++mt) {
        const short8 a = *(const short8*)&h_lds[mt * 16 + l16][kc * 32 + quad * 8];
#pragma unroll
        for (int g = 0; g < 4; ++g)
          acc[mt][g] =
              __builtin_amdgcn_mfma_f32_16x16x32_bf16(a, wfrag[g][kc], acc[mt][g], 0, 0, 0);
      }
    }

    // 5. gates + state update; publish tagged slice (write-through u32)
    unsigned* __restrict__ dst32 = hgs + ((((size_t)d * 2 + (s & 1)) * 4 + q) << 12);
    const unsigned tag = ((unsigned)(s + 1)) << 16;
    __hip_bfloat16 hbf[16];
#pragma unroll
    for (int mt = 0; mt < 4; ++mt)
#pragma unroll
      for (int r = 0; r < 4; ++r) {
        const int idx = mt * 4 + r, b = mt * 16 + quad * 4 + r;
        const float fg = sigmf(acc[mt][0][r]);
        const float ig = sigmf(acc[mt][1][r]);
        const float gg = tanh_fast(acc[mt][2][r]);
        const float og = sigmf(acc[mt][3][r]);
        const float cn = fg * c_reg[idx] + ig * gg;
        const float hn = og * tanh_fast(cn);
        if (t < len_b[idx]) {
          c_reg[idx] = cn;
          h_reg[idx] = hn;
        }
        hbf[idx] = __float2bfloat16(h_reg[idx]);
        __hip_atomic_store(dst32 + b * 64 + w * 16 + l16,
                           tag | (unsigned)*(unsigned short*)&hbf[idx], __ATOMIC_RELAXED,
                           __HIP_MEMORY_SCOPE_AGENT);
      }

    // hint flag: this wave's 16 payload stores are issued (program order);
    // hint-only, correctness stays with the tag sweep.
    if (L == 0)
      __hip_atomic_store(hflags + (((d * 2 + (s & 1)) * 4 + q) * 4 + w),
                         (unsigned)(s + 1), __ATOMIC_RELAXED, __HIP_MEMORY_SCOPE_AGENT);

    __syncthreads();  // LDS overwrite guard

#pragma unroll
    for (int mt = 0; mt < 4; ++mt)
#pragma unroll
      for (int r = 0; r < 4; ++r)
        h_lds[mt * 16 + quad * 4 + r][u] = hbf[mt * 4 + r];

    if (WRITE_SEQ) {
#pragma unroll
      for (int mt = 0; mt < 4; ++mt)
#pragma unroll
        for (int r = 0; r < 4; ++r) {
          const int b = mt * 16 + quad * 4 + r;
          seq0[((size_t)t * 64 + b) * 512 + d * 256 + u] = hbf[mt * 4 + r];
        }
    }
  }

#pragma unroll
  for (int mt = 0; mt < 4; ++mt)
#pragma unroll
    for (int r = 0; r < 4; ++r) {
      const int idx = mt * 4 + r, b = mt * 16 + quad * 4 + r;
      cstate[((size_t)(d * 64 + b) << 8) + u] = c_reg[idx];
      hstate[((size_t)(d * 64 + b) << 8) + u] = h_reg[idx];
    }
}

// ===========================================================================
// SLOW FALLBACK PATH (round-2 passing version, used when ws is too small)
// ===========================================================================
template <typename TW, int XK, bool WRITE_SEQ>
__device__ __forceinline__ void lstm_body(const int* __restrict__ x, const TW* __restrict__ E,
                                          const __hip_bfloat16* __restrict__ seq_in,
                                          const TW* __restrict__ W, const TW* __restrict__ bias,
                                          const int len, const int b, const int dir,
                                          __hip_bfloat16* __restrict__ seq_out,
                                          float* __restrict__ hfin) {
  const int j = threadIdx.x;
  __shared__ float h[Hn];
  __shared__ float xb[XK];
  float hj = 0.0f, cj = 0.0f;
  h[j] = 0.0f;
  const float bfj = ldf(bias, j);
  const float bij = ldf(bias, Hn + j);
  const float bgj = ldf(bias, 2 * Hn + j);
  const float boj = ldf(bias, 3 * Hn + j);
  __syncthreads();
  for (int s = 0; s < Tn; ++s) {
    const int t = dir ? (Tn - 1 - s) : s;
    const bool active = (t < len);
    if (active) {
      if constexpr (XK == Dn) {
        const int tok = x[b * Tn + t];
        xb[j] = ldf(E, (long)tok * Dn + j);
      } else {
        const long base = ((long)(b * Tn + t)) * (2 * Hn);
        xb[j] = __bfloat162float(seq_in[base + j]);
        xb[j + Hn] = __bfloat162float(seq_in[base + j + Hn]);
      }
      __syncthreads();
      float af = bfj, ai = bij, ag = bgj, ao = boj;
#pragma unroll 4
      for (int k = 0; k < Hn; ++k) {
        const float hk = h[k];
        const long r = (long)k * (4 * Hn);
        af += hk * ldf(W, r + j);
        ai += hk * ldf(W, r + Hn + j);
        ag += hk * ldf(W, r + 2 * Hn + j);
        ao += hk * ldf(W, r + 3 * Hn + j);
      }
#pragma unroll 4
      for (int k = 0; k < XK; ++k) {
        const float xk = xb[k];
        const long r = (long)(Hn + k) * (4 * Hn);
        af += xk * ldf(W, r + j);
        ai += xk * ldf(W, r + Hn + j);
        ag += xk * ldf(W, r + 2 * Hn + j);
        ao += xk * ldf(W, r + 3 * Hn + j);
      }
      const float fg = 1.0f / (1.0f + expf(-af));
      const float ig = 1.0f / (1.0f + expf(-ai));
      const float gg = tanhf(ag);
      const float og = 1.0f / (1.0f + expf(-ao));
      const float cn = fg * cj + ig * gg;
      const float hn = og * tanhf(cn);
      __syncthreads();
      hj = hn;
      cj = cn;
      h[j] = hn;
      __syncthreads();
    }
    if constexpr (WRITE_SEQ) {
      seq_out[((long)(b * Tn + t)) * (2 * Hn) + dir * Hn + j] = __float2bfloat16(hj);
    }
  }
  if constexpr (!WRITE_SEQ) hfin[(dir * Bn + b) * Hn + j] = hj;
}

template <int XK, bool WRITE_SEQ>
__global__ void k_lstm(const int* __restrict__ x, const void* __restrict__ E,
                       const __hip_bfloat16* __restrict__ seq_in, const void* __restrict__ Wf,
                       const void* __restrict__ bf, const void* __restrict__ Wb,
                       const void* __restrict__ bb, const int* __restrict__ lengths,
                       const int* __restrict__ flag, __hip_bfloat16* __restrict__ seq_out,
                       float* __restrict__ hfin) {
  const int b = blockIdx.x & (Bn - 1);
  const int dir = blockIdx.x >> 6;
  const int len = lengths[b];
  const void* W = dir ? Wb : Wf;
  const void* bias = dir ? bb : bf;
  if (flag[0]) {
    lstm_body<float, XK, WRITE_SEQ>(x, (const float*)E, seq_in, (const float*)W,
                                    (const float*)bias, len, b, dir, seq_out, hfin);
  } else {
    lstm_body<__hip_bfloat16, XK, WRITE_SEQ>(x, (const __hip_bfloat16*)E, seq_in,
                                             (const __hip_bfloat16*)W, (const __hip_bfloat16*)bias,
                                             len, b, dir, seq_out, hfin);
  }
}

// ---------------------------------------------------------------------------
template <typename TW>
__device__ __forceinline__ void fc_body(const float* __restrict__ hfin, const TW* __restrict__ Wfc,
                                        const TW* __restrict__ bfc, TW* __restrict__ out) {
  const int idx = threadIdx.x;
  const int b = idx >> 1;
  const int cc = idx & 1;
  float acc = ldf(bfc, cc);
  for (int k = 0; k < Hn; ++k) acc += hfin[(0 * Bn + b) * Hn + k] * ldf(Wfc, k * 2 + cc);
  for (int k = 0; k < Hn; ++k) acc += hfin[(1 * Bn + b) * Hn + k] * ldf(Wfc, (Hn + k) * 2 + cc);
  if constexpr (sizeof(TW) == 2) {
    out[b * 2 + cc] = __float2bfloat16(acc);
  } else {
    out[b * 2 + cc] = acc;
  }
}

__global__ void k_fc(const float* __restrict__ hfin, const void* __restrict__ Wfc,
                     const void* __restrict__ bfc, const int* __restrict__ flag,
                     void* __restrict__ out) {
  if (flag[0]) {
    fc_body<float>(hfin, (const float*)Wfc, (const float*)bfc, (float*)out);
  } else {
    fc_body<__hip_bfloat16>(hfin, (const __hip_bfloat16*)Wfc, (const __hip_bfloat16*)bfc,
                            (__hip_bfloat16*)out);
  }
}

// ---------------------------------------------------------------------------
extern "C" void kernel_launch(void* const* d_in, const int* in_sizes, int n_in,
                              void* d_out, int out_size, void* d_ws, size_t ws_size,
                              hipStream_t stream) {
  const int* x = (const int*)d_in[0];
  const void* E = d_in[1];
  const void* Wf0 = d_in[2];
  const void* bf0 = d_in[3];
  const void* Wb0 = d_in[4];
  const void* bb0 = d_in[5];
  const void* Wf1 = d_in[6];
  const void* bf1 = d_in[7];
  const void* Wb1 = d_in[8];
  const void* bb1 = d_in[9];
  const void* Wfc = d_in[10];
  const void* bfc = d_in[11];

  char* ws = (char*)d_ws;
  int* flag = (int*)ws;             // @0
  int* lengths = (int*)(ws + 256);

  const size_t MB = 1ull << 20;
  const size_t KB = 1024;

  k_detect<<<1, 256, 0, stream>>>((const unsigned short*)E, flag);
  k_lengths<<<Bn, 256, 0, stream>>>(x, lengths);

  // fixed 73 MB (weights/state/seq0) + one bf16 xproj slot Tc*256KB (reused L0/L1)
  int Tc = 0;
  {
    const size_t fixed = 73 * MB;
    const int cands[7] = {1024, 512, 256, 128, 64, 32, 16};
    for (int i = 0; i < 7; ++i)
      if (fixed + (size_t)cands[i] * 256 * KB <= ws_size) { Tc = cands[i]; break; }
  }

  if (Tc > 0) {
    float* biasbuf = (float*)(ws + 4096);                    // 16 KB
    __hip_bfloat16* whT = (__hip_bfloat16*)(ws + 1 * MB);    // [4][1024][256] = 2 MB
    __hip_bfloat16* wxT0 = (__hip_bfloat16*)(ws + 3 * MB);   // [2][1024][256] = 1 MB
    __hip_bfloat16* wxT1 = (__hip_bfloat16*)(ws + 4 * MB);   // [2][1024][512] = 2 MB
    unsigned* hgs0 = (unsigned*)(ws + 6 * MB);               // 256 KB
    unsigned* hgs1 = (unsigned*)(ws + 6 * MB + 256 * KB);    // 256 KB
    unsigned* hflags0 = (unsigned*)(ws + 6 * MB + 512 * KB); // 256 B (hint flags L0)
    unsigned* hflags1 = (unsigned*)(ws + 6 * MB + 513 * KB); // 256 B (hint flags L1)
    float* cstate0 = (float*)(ws + 7 * MB);                  // 128 KB
    float* hstate0 = (float*)(ws + 7 * MB + 128 * KB);       // 128 KB
    float* cstate1 = (float*)(ws + 7 * MB + 256 * KB);       // 128 KB
    float* hstate1 = (float*)(ws + 7 * MB + 384 * KB);       // 128 KB
    __hip_bfloat16* seq0 = (__hip_bfloat16*)(ws + 8 * MB);   // [1024][64][512] = 64 MB
    __hip_bfloat16* xsl = (__hip_bfloat16*)(ws + 73 * MB);   // [2][Tc][4][8][256][8] bf16

    k_prep_small<<<1, 256, 0, stream>>>(bf0, bb0, bf1, bb1, flag, biasbuf);
    k_prepw<<<dim3(12, 16, 4), 256, 0, stream>>>(Wf0, Wb0, Wf1, Wb1, flag, whT, wxT0, wxT1);
    // zero both mailboxes + hint flags: kill stale tags
    hipMemsetAsync(hgs0, 0, 516 * KB, stream);

    const int P = Tn / Tc;
    const int Mrows = Tc * 64;
    const int ntiles = (Mrows / 128) * 16;
    // layer 0
    for (int p = 0; p < P; ++p) {
      const int s0 = p * Tc;
      const int t0f = s0, t0b = Tn - s0 - Tc;
      k_xproj3<256, true><<<ntiles, 256, 0, stream>>>(x, E, flag, nullptr, nullptr, wxT0, xsl,
                                                      Mrows, t0f, t0b);
      k_lstm_fast<true><<<64, 256, 0, stream>>>(whT, xsl, biasbuf, lengths, hgs0, hflags0,
                                                cstate0, hstate0, seq0, s0, Tc);
    }
    // layer 1
    for (int p = 0; p < P; ++p) {
      const int s0 = p * Tc;
      const int t0f = s0, t0b = Tn - s0 - Tc;
      k_xproj3<512, false><<<ntiles, 256, 0, stream>>>(
          x, E, flag, seq0 + (size_t)t0f * 64 * 512, seq0 + (size_t)t0b * 64 * 512, wxT1, xsl,
          Mrows, 0, 0);
      k_lstm_fast<false><<<64, 256, 0, stream>>>(whT + 2 * 1024 * 256, xsl, biasbuf + 2048,
                                                 lengths, hgs1, hflags1, cstate1, hstate1,
                                                 nullptr, s0, Tc);
    }
    k_fc<<<1, 128, 0, stream>>>(hstate1, Wfc, bfc, flag, d_out);
  } else {
    // slow fallback (round-2 passing path)
    __hip_bfloat16* seq0 = (__hip_bfloat16*)(ws + 64 * 1024);
    const size_t seq0_bytes = (size_t)Bn * Tn * 2 * Hn * sizeof(__hip_bfloat16);
    float* hfin = (float*)(ws + 64 * 1024 + seq0_bytes);
    k_lstm<Dn, true><<<2 * Bn, 256, 0, stream>>>(x, E, nullptr, Wf0, bf0, Wb0, bb0, lengths, flag,
                                                 seq0, nullptr);
    k_lstm<2 * Hn, false><<<2 * Bn, 256, 0, stream>>>(x, E, seq0, Wf1, bf1, Wb1, bb1, lengths,
                                                      flag, nullptr, hfin);
    k_fc<<<1, 128, 0, stream>>>(hfin, Wfc, bfc, flag, d_out);
  }
}

// Round 10
// 14906.712 us; speedup vs baseline: 1.6328x; 1.0140x over previous
//
#include <hip/hip_runtime.h>
#include <hip/hip_bf16.h>
#include <math.h>

// Problem constants: V=32000, D=256, H=256, L=2, C=2, B=64, T=1024, PAD=0
namespace {
constexpr int Bn = 64;
constexpr int Tn = 1024;
constexpr int Dn = 256;
constexpr int Hn = 256;
}

typedef __attribute__((ext_vector_type(8))) short short8;
typedef __attribute__((ext_vector_type(4))) float f32x4;

template <typename T>
__device__ __forceinline__ float ldf(const T* p, long i);
template <>
__device__ __forceinline__ float ldf<float>(const float* p, long i) { return p[i]; }
template <>
__device__ __forceinline__ float ldf<__hip_bfloat16>(const __hip_bfloat16* p, long i) {
  return __bfloat162float(p[i]);
}

__device__ __forceinline__ float sigmf(float x) { return 1.0f / (1.0f + __expf(-x)); }
__device__ __forceinline__ float tanh_fast(float x) {
  return 1.0f - 2.0f / (__expf(2.0f * x) + 1.0f);
}

// LDS-only barrier: orders all DS ops across the block WITHOUT draining
// outstanding global loads/stores (hipcc's __syncthreads emits a full
// s_waitcnt vmcnt(0) which serializes the mailbox/seq0 store drain into
// the recurrence critical path). lgkmcnt(0) + "memory" clobber covers the
// LDS ordering; sched_barrier(0) pins against compiler reordering (rule #18).
__device__ __forceinline__ void lds_barrier() {
  asm volatile("s_waitcnt lgkmcnt(0)" ::: "memory");
  __builtin_amdgcn_sched_barrier(0);
  __builtin_amdgcn_s_barrier();
  __builtin_amdgcn_sched_barrier(0);
}

// ---------------------------------------------------------------------------
// Dtype detector (validated round 2: flag=1 -> f32 inputs).
// ---------------------------------------------------------------------------
__global__ void k_detect(const unsigned short* __restrict__ e, int* __restrict__ flag) {
  __shared__ int sbuf[256];
  int bad = 0;
  for (int i = threadIdx.x; i < 4096; i += 256) {
    const unsigned short v = e[i];
    const int ex = (v >> 7) & 0xFF;
    bad += (ex >= 137) ? 1 : 0;
  }
  sbuf[threadIdx.x] = bad;
  __syncthreads();
  for (int s = 128; s > 0; s >>= 1) {
    if (threadIdx.x < s) sbuf[threadIdx.x] += sbuf[threadIdx.x + s];
    __syncthreads();
  }
  if (threadIdx.x == 0) flag[0] = (sbuf[0] > 64) ? 1 : 0;
}

__global__ void k_lengths(const int* __restrict__ x, int* __restrict__ len) {
  const int b = blockIdx.x;
  int cnt = 0;
  for (int t = threadIdx.x; t < Tn; t += blockDim.x) cnt += (x[b * Tn + t] != 0) ? 1 : 0;
  __shared__ int sbuf[256];
  sbuf[threadIdx.x] = cnt;
  __syncthreads();
  for (int s = 128; s > 0; s >>= 1) {
    if (threadIdx.x < s) sbuf[threadIdx.x] += sbuf[threadIdx.x + s];
    __syncthreads();
  }
  if (threadIdx.x == 0) len[b] = sbuf[0];
}

// ===========================================================================
// FAST PATH
// ===========================================================================

// biases -> f32 [4][1024] (order: f0,b0,f1,b1).
__global__ void k_prep_small(const void* b0f, const void* b0b, const void* b1f, const void* b1b,
                             const int* __restrict__ flag, float* __restrict__ biasbuf) {
  const int tid = threadIdx.x;
  const bool isf32 = flag[0] != 0;
  for (int idx = tid; idx < 4096; idx += 256) {
    const int j = idx >> 10, col = idx & 1023;
    const void* src = (j == 0) ? b0f : (j == 1) ? b0b : (j == 2) ? b1f : b1b;
    biasbuf[idx] = isf32 ? ((const float*)src)[col]
                         : __bfloat162float(((const __hip_bfloat16*)src)[col]);
  }
}

// Transpose+convert W[(H+XK) x 1024] -> WhT bf16 [1024][256], WxT bf16 [1024][XK].
__global__ void k_prepw(const void* W0, const void* W1, const void* W2, const void* W3,
                        const int* __restrict__ flag, __hip_bfloat16* __restrict__ whT,
                        __hip_bfloat16* __restrict__ wxT0, __hip_bfloat16* __restrict__ wxT1) {
  const int j = blockIdx.z;
  const int rows = (j < 2) ? 512 : 768;
  const int bx = blockIdx.x;
  if (bx * 64 >= rows) return;
  const int by = blockIdx.y;
  const void* W = (j == 0) ? W0 : (j == 1) ? W1 : (j == 2) ? W2 : W3;
  const bool isf32 = flag[0] != 0;
  __shared__ float tile[64][65];
  const int tid = threadIdx.x;
  const int c = tid & 63, r4 = tid >> 6;
#pragma unroll
  for (int rep = 0; rep < 16; ++rep) {
    const int rr = r4 * 16 + rep;
    const size_t idx = (size_t)(bx * 64 + rr) * 1024 + by * 64 + c;
    tile[rr][c] = isf32 ? ((const float*)W)[idx]
                        : __bfloat162float(((const __hip_bfloat16*)W)[idx]);
  }
  __syncthreads();
  const int kk = tid & 63;
#pragma unroll
  for (int rep = 0; rep < 16; ++rep) {
    const int a = r4 * 16 + rep;
    const int n = by * 64 + a;
    const int k = bx * 64 + kk;
    const __hip_bfloat16 v = __float2bfloat16(tile[kk][a]);
    if (k < 256) {
      whT[(size_t)j * (1024 * 256) + (size_t)n * 256 + k] = v;
    } else {
      const int k2 = k - 256;
      if (j < 2)
        wxT0[(size_t)j * (1024 * 256) + (size_t)n * 256 + k2] = v;
      else
        wxT1[(size_t)(j - 2) * (1024 * 512) + (size_t)n * 512 + k2] = v;
    }
  }
}

// ---------------------------------------------------------------------------
// xproj GEMM v4 (validated rounds 2-6): 128x128 tile/block, B in LDS, A from
// global/gather; OUTPUT in the consumer-native layout of k_lstm_fast:
//   xp[d][tl][q 0..3][jv 0..7][tid 0..255][8 bf16]   (per (d,tl): 128 KB)
// Producer mapping (verified): tl = bx*2+(w>>1); jv = (by>>1)*2+(w&1);
//   q = (by&1)*2+(nt>>2); tid_c = (nt&3)*64+quad*16+l16; elem = mt2*4+r.
// ---------------------------------------------------------------------------
template <int K, bool GATHER>
__launch_bounds__(256, 2)
__global__ void k_xproj3(const int* __restrict__ x, const void* __restrict__ E,
                         const int* __restrict__ flag, const __hip_bfloat16* __restrict__ Af,
                         const __hip_bfloat16* __restrict__ Ab,
                         const __hip_bfloat16* __restrict__ WT,  // [2][1024][K]
                         __hip_bfloat16* __restrict__ xp,        // [2][Tc][4][8][256][8]
                         const int Mrows, const int t0f, const int t0b) {
  constexpr int KC = 256;
  __shared__ __hip_bfloat16 Btile[128][KC + 8];
  const int tix = blockIdx.x;
  const int by = tix & 7;
  const int dz = (tix >> 3) & 1;
  const int bx = tix >> 4;
  const int tid = threadIdx.x, w = tid >> 6, L = tid & 63, quad = L >> 4, l16 = L & 15;
  const __hip_bfloat16* __restrict__ WTd = WT + (size_t)dz * (1024 * K);
  __hip_bfloat16* __restrict__ o = xp + (size_t)dz * Mrows * 1024;

  f32x4 acc[2][8];
#pragma unroll
  for (int mt = 0; mt < 2; ++mt)
#pragma unroll
    for (int nt = 0; nt < 8; ++nt) {
      acc[mt][nt][0] = 0.f; acc[mt][nt][1] = 0.f; acc[mt][nt][2] = 0.f; acc[mt][nt][3] = 0.f;
    }

  const int row0 = bx * 128 + w * 32 + l16;  // a0 row; a1 = row0+16
  const __hip_bfloat16* arow0b = nullptr;
  const __hip_bfloat16* arow1b = nullptr;
  const float* arow0f = nullptr;
  const float* arow1f = nullptr;
  bool isf32 = false;
  if constexpr (GATHER) {
    isf32 = flag[0] != 0;
    const int t0 = (dz ? t0b : t0f) + (row0 >> 6), b0 = row0 & 63;
    const int r1 = row0 + 16;
    const int t1 = (dz ? t0b : t0f) + (r1 >> 6), b1 = r1 & 63;
    const int tok0 = x[b0 * Tn + t0];
    const int tok1 = x[b1 * Tn + t1];
    if (isf32) {
      arow0f = (const float*)E + (size_t)tok0 * Dn;
      arow1f = (const float*)E + (size_t)tok1 * Dn;
    } else {
      arow0b = (const __hip_bfloat16*)E + (size_t)tok0 * Dn;
      arow1b = (const __hip_bfloat16*)E + (size_t)tok1 * Dn;
    }
  } else {
    const __hip_bfloat16* A = dz ? Ab : Af;
    arow0b = A + (size_t)row0 * K;
    arow1b = A + (size_t)(row0 + 16) * K;
  }

  for (int ch = 0; ch < K / KC; ++ch) {
    if (ch) __syncthreads();
    // stage B chunk: 128 cols x 256 shorts
#pragma unroll
    for (int it = 0; it < 16; ++it) {
      const int idx = it * 256 + tid;
      const int col = idx >> 5, seg = idx & 31;
      *(short8*)&Btile[col][seg * 8] =
          *(const short8*)(WTd + (size_t)(by * 128 + col) * K + ch * KC + seg * 8);
    }
    __syncthreads();

#pragma unroll
    for (int kc = 0; kc < 8; ++kc) {
      short8 a0, a1;
      if constexpr (GATHER) {
        if (isf32) {
#pragma unroll
          for (int jj = 0; jj < 8; ++jj) {
            __hip_bfloat16 h0 = __float2bfloat16(arow0f[kc * 32 + quad * 8 + jj]);
            __hip_bfloat16 h1 = __float2bfloat16(arow1f[kc * 32 + quad * 8 + jj]);
            a0[jj] = *(const short*)&h0;
            a1[jj] = *(const short*)&h1;
          }
        } else {
          a0 = *(const short8*)(arow0b + kc * 32 + quad * 8);
          a1 = *(const short8*)(arow1b + kc * 32 + quad * 8);
        }
      } else {
        a0 = *(const short8*)(arow0b + ch * KC + kc * 32 + quad * 8);
        a1 = *(const short8*)(arow1b + ch * KC + kc * 32 + quad * 8);
      }
#pragma unroll
      for (int nt = 0; nt < 8; ++nt) {
        const short8 b = *(const short8*)&Btile[nt * 16 + l16][kc * 32 + quad * 8];
        acc[0][nt] = __builtin_amdgcn_mfma_f32_16x16x32_bf16(a0, b, acc[0][nt], 0, 0, 0);
        acc[1][nt] = __builtin_amdgcn_mfma_f32_16x16x32_bf16(a1, b, acc[1][nt], 0, 0, 0);
      }
    }
  }

  // --- epilogue: consumer-native layout, fully coalesced 16B stores ---
  {
    const int tl = bx * 2 + (w >> 1);
    const int jv = (by >> 1) * 2 + (w & 1);
    const int qbase = (by & 1) << 1;
    __hip_bfloat16* __restrict__ ob = o + (size_t)tl * 65536 + (size_t)jv * 2048;
#pragma unroll
    for (int nt = 0; nt < 8; ++nt) {
      const int q_ = qbase + (nt >> 2);
      const int tid_c = (nt & 3) * 64 + quad * 16 + l16;
      short8 sv;
#pragma unroll
      for (int r = 0; r < 4; ++r) {
        __hip_bfloat16 h0 = __float2bfloat16(acc[0][nt][r]);
        __hip_bfloat16 h1 = __float2bfloat16(acc[1][nt][r]);
        sv[r] = *(const short*)&h0;
        sv[4 + r] = *(const short*)&h1;
      }
      *(short8*)(ob + (size_t)q_ * 16384 + tid_c * 8) = sv;
    }
  }
}

// ---------------------------------------------------------------------------
// Phased recurrent layer v11: round-9 body (hint flags + validated tagged
// sweep + XCD-aware placement) with the two in-loop __syncthreads replaced
// by LDS-ONLY raw barriers (lgkmcnt(0) + s_barrier). hipcc's __syncthreads
// drains vmcnt(0) -- serializing the 16KB mailbox + 32KB seq0 store drain
// into the recurrence chain and delaying publish visibility. With raw
// barriers the stores drain in background during the partner's compute.
// Protocol safety unchanged: tags are the correctness mechanism; per-thread
// same-address stores are location-ordered; parity flow control bounds
// producer lead to < 2 steps; seq0's only consumer is after dispatch end.
// ---------------------------------------------------------------------------
template <bool WRITE_SEQ>
__launch_bounds__(256, 1) __global__
void k_lstm_fast(const __hip_bfloat16* __restrict__ WhT,   // [2][1024][256] this layer
                 const __hip_bfloat16* __restrict__ xproj,  // [2][Tc][4][8][256][8] bf16
                 const float* __restrict__ biasL,           // [2][1024] this layer
                 const int* __restrict__ lengths,
                 unsigned* __restrict__ hgs,     // [2 d][2 par][4 q][64 b][64 u] u32
                 unsigned* __restrict__ hflags,  // [2 d][2 par][4 q][4 w] u32 hint flags
                 float* __restrict__ cstate, float* __restrict__ hstate,  // [2][64][256]
                 __hip_bfloat16* __restrict__ seq0,         // [T][64][512]
                 const int s0, const int Tc) {
  // XCD-aware remap: worker iff (bid&7)<2 && (bid>>3)<4; d = bid&7, q = bid>>3.
  const int xcd = blockIdx.x & 7;
  const int kq = blockIdx.x >> 3;
  if (xcd >= 2 || kq >= 4) return;
  const int d = xcd;
  const int q = kq;
  const int tid = threadIdx.x;
  const int w = tid >> 6, L = tid & 63, quad = L >> 4, l16 = L & 15;
  const int u = q * 64 + w * 16 + l16;

  __shared__ __hip_bfloat16 h_lds[64][272];
  for (int idx = tid; idx < 64 * 272; idx += 256) (&h_lds[0][0])[idx] = __float2bfloat16(0.0f);

  const __hip_bfloat16* __restrict__ Wd = WhT + (size_t)d * (1024 * 256);
  short8 wfrag[4][8];
#pragma unroll
  for (int g = 0; g < 4; ++g)
#pragma unroll
    for (int kc = 0; kc < 8; ++kc)
      wfrag[g][kc] = *(const short8*)(Wd + (size_t)(g * 256 + u) * 256 + kc * 32 + quad * 8);

  float bz[4];
#pragma unroll
  for (int g = 0; g < 4; ++g) bz[g] = biasL[d * 1024 + g * 256 + u];

  float c_reg[16], h_reg[16];
  int len_b[16];
#pragma unroll
  for (int mt = 0; mt < 4; ++mt)
#pragma unroll
    for (int r = 0; r < 4; ++r) {
      const int idx = mt * 4 + r;
      const int b = mt * 16 + quad * 4 + r;
      len_b[idx] = lengths[b];
      if (s0 == 0) {
        c_reg[idx] = 0.0f;
        h_reg[idx] = 0.0f;
      } else {
        c_reg[idx] = cstate[((size_t)(d * 64 + b) << 8) + u];
        h_reg[idx] = hstate[((size_t)(d * 64 + b) << 8) + u];
      }
    }
  __syncthreads();
#pragma unroll
  for (int mt = 0; mt < 4; ++mt)
#pragma unroll
    for (int r = 0; r < 4; ++r)
      h_lds[mt * 16 + quad * 4 + r][u] = __float2bfloat16(h_reg[mt * 4 + r]);
  __syncthreads();

  // base of this (d, q, tid)'s xproj stream
  const __hip_bfloat16* __restrict__ xq =
      xproj + (size_t)d * Tc * 65536 + (size_t)q * 16384 + (size_t)tid * 8;

  for (int sl = 0; sl < Tc; ++sl) {
    const int s = s0 + sl;
    const int t = d ? (Tn - 1 - s) : s;
    const int tl = d ? (Tc - 1 - sl) : sl;

    // 1. issue coalesced xproj loads (consumed after the exchange -> latency
    //    hides under the spin; only 32 VGPRs live across it)
    short8 xv[8];
    {
      const __hip_bfloat16* __restrict__ src = xq + (size_t)tl * 65536;
#pragma unroll
      for (int jv = 0; jv < 8; ++jv) xv[jv] = *(const short8*)(src + jv * 2048);
    }

    // 2. exchange: hint-flag pre-spin, then the validated tagged sweep
    if (s > 0) {
      if (w != q) {
        const unsigned exp = (unsigned)s;
        // 2a. cheap hint spin: 4x4B uniform loads per retry
        {
          const unsigned* __restrict__ f4 =
              hflags + (((d * 2 + ((s - 1) & 1)) * 4 + w) * 4);
          for (;;) {
            const unsigned f0 =
                __hip_atomic_load(f4 + 0, __ATOMIC_RELAXED, __HIP_MEMORY_SCOPE_AGENT);
            const unsigned f1 =
                __hip_atomic_load(f4 + 1, __ATOMIC_RELAXED, __HIP_MEMORY_SCOPE_AGENT);
            const unsigned f2 =
                __hip_atomic_load(f4 + 2, __ATOMIC_RELAXED, __HIP_MEMORY_SCOPE_AGENT);
            const unsigned f3 =
                __hip_atomic_load(f4 + 3, __ATOMIC_RELAXED, __HIP_MEMORY_SCOPE_AGENT);
            if (f0 >= exp && f1 >= exp && f2 >= exp && f3 >= exp) break;
            __builtin_amdgcn_s_sleep(1);
          }
        }
        // 2b. validated tagged-payload sweep (normally single pass now)
        const unsigned long long* __restrict__ src64 =
            (const unsigned long long*)(hgs + ((((size_t)d * 2 + ((s - 1) & 1)) * 4 + w) << 12));
        unsigned long long v[32];
        unsigned pend = 0xFFFFFFFFu;
        int tries = 0;
        do {
          if (tries++) __builtin_amdgcn_s_sleep(1);
#pragma unroll
          for (int i = 0; i < 32; ++i)
            if (pend & (1u << i))
              v[i] = __hip_atomic_load(src64 + i * 64 + L, __ATOMIC_RELAXED,
                                       __HIP_MEMORY_SCOPE_AGENT);
#pragma unroll
          for (int i = 0; i < 32; ++i)
            if (pend & (1u << i)) {
              const unsigned lo = (unsigned)v[i], hi = (unsigned)(v[i] >> 32);
              if ((lo >> 16) == exp && (hi >> 16) == exp) pend &= ~(1u << i);
            }
        } while (pend);
#pragma unroll
        for (int i = 0; i < 32; ++i) {
          const int j = i * 64 + L;
          const unsigned lo = (unsigned)v[i], hi = (unsigned)(v[i] >> 32);
          const unsigned packed = (lo & 0xFFFFu) | (hi << 16);
          *(unsigned*)&h_lds[j >> 5][w * 64 + (j & 31) * 2] = packed;
        }
      }
      lds_barrier();  // LDS-only: no vmcnt drain on the critical path
    }

    // 3. unpack xproj + f32 bias -> acc
    f32x4 acc[4][4];
#pragma unroll
    for (int mt = 0; mt < 4; ++mt)
#pragma unroll
      for (int g = 0; g < 4; ++g) {
        const short8 v = xv[g * 2 + (mt >> 1)];
#pragma unroll
        for (int r = 0; r < 4; ++r) {
          const short sv = v[(mt & 1) * 4 + r];
          acc[mt][g][r] = __bfloat162float(*(const __hip_bfloat16*)&sv) + bz[g];
        }
      }

    // 4. z += h @ Wh
#pragma unroll
    for (int kc = 0; kc < 8; ++kc) {
#pragma unroll
      for (int mt = 0; mt < 4; ++mt) {
        const short8 a = *(const short8*)&h_lds[mt * 16 + l16][kc * 32 + quad * 8];
#pragma unroll
        for (int g = 0; g < 4; ++g)
          acc[mt][g] =
              __builtin_amdgcn_mfma_f32_16x16x32_bf16(a, wfrag[g][kc], acc[mt][g], 0, 0, 0);
      }
    }

    // 5. gates + state update; publish tagged slice (write-through u32)
    unsigned* __restrict__ dst32 = hgs + ((((size_t)d * 2 + (s & 1)) * 4 + q) << 12);
    const unsigned tag = ((unsigned)(s + 1)) << 16;
    __hip_bfloat16 hbf[16];
#pragma unroll
    for (int mt = 0; mt < 4; ++mt)
#pragma unroll
      for (int r = 0; r < 4; ++r) {
        const int idx = mt * 4 + r, b = mt * 16 + quad * 4 + r;
        const float fg = sigmf(acc[mt][0][r]);
        const float ig = sigmf(acc[mt][1][r]);
        const float gg = tanh_fast(acc[mt][2][r]);
        const float og = sigmf(acc[mt][3][r]);
        const float cn = fg * c_reg[idx] + ig * gg;
        const float hn = og * tanh_fast(cn);
        if (t < len_b[idx]) {
          c_reg[idx] = cn;
          h_reg[idx] = hn;
        }
        hbf[idx] = __float2bfloat16(h_reg[idx]);
        __hip_atomic_store(dst32 + b * 64 + w * 16 + l16,
                           tag | (unsigned)*(unsigned short*)&hbf[idx], __ATOMIC_RELAXED,
                           __HIP_MEMORY_SCOPE_AGENT);
      }

    // hint flag: this wave's 16 payload stores are issued (program order);
    // hint-only, correctness stays with the tag sweep.
    if (L == 0)
      __hip_atomic_store(hflags + (((d * 2 + (s & 1)) * 4 + q) * 4 + w),
                         (unsigned)(s + 1), __ATOMIC_RELAXED, __HIP_MEMORY_SCOPE_AGENT);

    lds_barrier();  // LDS overwrite guard; global stores drain in background

#pragma unroll
    for (int mt = 0; mt < 4; ++mt)
#pragma unroll
      for (int r = 0; r < 4; ++r)
        h_lds[mt * 16 + quad * 4 + r][u] = hbf[mt * 4 + r];

    if (WRITE_SEQ) {
#pragma unroll
      for (int mt = 0; mt < 4; ++mt)
#pragma unroll
        for (int r = 0; r < 4; ++r) {
          const int b = mt * 16 + quad * 4 + r;
          seq0[((size_t)t * 64 + b) * 512 + d * 256 + u] = hbf[mt * 4 + r];
        }
    }
  }

#pragma unroll
  for (int mt = 0; mt < 4; ++mt)
#pragma unroll
    for (int r = 0; r < 4; ++r) {
      const int idx = mt * 4 + r, b = mt * 16 + quad * 4 + r;
      cstate[((size_t)(d * 64 + b) << 8) + u] = c_reg[idx];
      hstate[((size_t)(d * 64 + b) << 8) + u] = h_reg[idx];
    }
}

// ===========================================================================
// SLOW FALLBACK PATH (round-2 passing version, used when ws is too small)
// ===========================================================================
template <typename TW, int XK, bool WRITE_SEQ>
__device__ __forceinline__ void lstm_body(const int* __restrict__ x, const TW* __restrict__ E,
                                          const __hip_bfloat16* __restrict__ seq_in,
                                          const TW* __restrict__ W, const TW* __restrict__ bias,
                                          const int len, const int b, const int dir,
                                          __hip_bfloat16* __restrict__ seq_out,
                                          float* __restrict__ hfin) {
  const int j = threadIdx.x;
  __shared__ float h[Hn];
  __shared__ float xb[XK];
  float hj = 0.0f, cj = 0.0f;
  h[j] = 0.0f;
  const float bfj = ldf(bias, j);
  const float bij = ldf(bias, Hn + j);
  const float bgj = ldf(bias, 2 * Hn + j);
  const float boj = ldf(bias, 3 * Hn + j);
  __syncthreads();
  for (int s = 0; s < Tn; ++s) {
    const int t = dir ? (Tn - 1 - s) : s;
    const bool active = (t < len);
    if (active) {
      if constexpr (XK == Dn) {
        const int tok = x[b * Tn + t];
        xb[j] = ldf(E, (long)tok * Dn + j);
      } else {
        const long base = ((long)(b * Tn + t)) * (2 * Hn);
        xb[j] = __bfloat162float(seq_in[base + j]);
        xb[j + Hn] = __bfloat162float(seq_in[base + j + Hn]);
      }
      __syncthreads();
      float af = bfj, ai = bij, ag = bgj, ao = boj;
#pragma unroll 4
      for (int k = 0; k < Hn; ++k) {
        const float hk = h[k];
        const long r = (long)k * (4 * Hn);
        af += hk * ldf(W, r + j);
        ai += hk * ldf(W, r + Hn + j);
        ag += hk * ldf(W, r + 2 * Hn + j);
        ao += hk * ldf(W, r + 3 * Hn + j);
      }
#pragma unroll 4
      for (int k = 0; k < XK; ++k) {
        const float xk = xb[k];
        const long r = (long)(Hn + k) * (4 * Hn);
        af += xk * ldf(W, r + j);
        ai += xk * ldf(W, r + Hn + j);
        ag += xk * ldf(W, r + 2 * Hn + j);
        ao += xk * ldf(W, r + 3 * Hn + j);
      }
      const float fg = 1.0f / (1.0f + expf(-af));
      const float ig = 1.0f / (1.0f + expf(-ai));
      const float gg = tanhf(ag);
      const float og = 1.0f / (1.0f + expf(-ao));
      const float cn = fg * cj + ig * gg;
      const float hn = og * tanhf(cn);
      __syncthreads();
      hj = hn;
      cj = cn;
      h[j] = hn;
      __syncthreads();
    }
    if constexpr (WRITE_SEQ) {
      seq_out[((long)(b * Tn + t)) * (2 * Hn) + dir * Hn + j] = __float2bfloat16(hj);
    }
  }
  if constexpr (!WRITE_SEQ) hfin[(dir * Bn + b) * Hn + j] = hj;
}

template <int XK, bool WRITE_SEQ>
__global__ void k_lstm(const int* __restrict__ x, const void* __restrict__ E,
                       const __hip_bfloat16* __restrict__ seq_in, const void* __restrict__ Wf,
                       const void* __restrict__ bf, const void* __restrict__ Wb,
                       const void* __restrict__ bb, const int* __restrict__ lengths,
                       const int* __restrict__ flag, __hip_bfloat16* __restrict__ seq_out,
                       float* __restrict__ hfin) {
  const int b = blockIdx.x & (Bn - 1);
  const int dir = blockIdx.x >> 6;
  const int len = lengths[b];
  const void* W = dir ? Wb : Wf;
  const void* bias = dir ? bb : bf;
  if (flag[0]) {
    lstm_body<float, XK, WRITE_SEQ>(x, (const float*)E, seq_in, (const float*)W,
                                    (const float*)bias, len, b, dir, seq_out, hfin);
  } else {
    lstm_body<__hip_bfloat16, XK, WRITE_SEQ>(x, (const __hip_bfloat16*)E, seq_in,
                                             (const __hip_bfloat16*)W, (const __hip_bfloat16*)bias,
                                             len, b, dir, seq_out, hfin);
  }
}

// ---------------------------------------------------------------------------
template <typename TW>
__device__ __forceinline__ void fc_body(const float* __restrict__ hfin, const TW* __restrict__ Wfc,
                                        const TW* __restrict__ bfc, TW* __restrict__ out) {
  const int idx = threadIdx.x;
  const int b = idx >> 1;
  const int cc = idx & 1;
  float acc = ldf(bfc, cc);
  for (int k = 0; k < Hn; ++k) acc += hfin[(0 * Bn + b) * Hn + k] * ldf(Wfc, k * 2 + cc);
  for (int k = 0; k < Hn; ++k) acc += hfin[(1 * Bn + b) * Hn + k] * ldf(Wfc, (Hn + k) * 2 + cc);
  if constexpr (sizeof(TW) == 2) {
    out[b * 2 + cc] = __float2bfloat16(acc);
  } else {
    out[b * 2 + cc] = acc;
  }
}

__global__ void k_fc(const float* __restrict__ hfin, const void* __restrict__ Wfc,
                     const void* __restrict__ bfc, const int* __restrict__ flag,
                     void* __restrict__ out) {
  if (flag[0]) {
    fc_body<float>(hfin, (const float*)Wfc, (const float*)bfc, (float*)out);
  } else {
    fc_body<__hip_bfloat16>(hfin, (const __hip_bfloat16*)Wfc, (const __hip_bfloat16*)bfc,
                            (__hip_bfloat16*)out);
  }
}

// ---------------------------------------------------------------------------
extern "C" void kernel_launch(void* const* d_in, const int* in_sizes, int n_in,
                              void* d_out, int out_size, void* d_ws, size_t ws_size,
                              hipStream_t stream) {
  const int* x = (const int*)d_in[0];
  const void* E = d_in[1];
  const void* Wf0 = d_in[2];
  const void* bf0 = d_in[3];
  const void* Wb0 = d_in[4];
  const void* bb0 = d_in[5];
  const void* Wf1 = d_in[6];
  const void* bf1 = d_in[7];
  const void* Wb1 = d_in[8];
  const void* bb1 = d_in[9];
  const void* Wfc = d_in[10];
  const void* bfc = d_in[11];

  char* ws = (char*)d_ws;
  int* flag = (int*)ws;             // @0
  int* lengths = (int*)(ws + 256);

  const size_t MB = 1ull << 20;
  const size_t KB = 1024;

  k_detect<<<1, 256, 0, stream>>>((const unsigned short*)E, flag);
  k_lengths<<<Bn, 256, 0, stream>>>(x, lengths);

  // fixed 73 MB (weights/state/seq0) + one bf16 xproj slot Tc*256KB (reused L0/L1)
  int Tc = 0;
  {
    const size_t fixed = 73 * MB;
    const int cands[7] = {1024, 512, 256, 128, 64, 32, 16};
    for (int i = 0; i < 7; ++i)
      if (fixed + (size_t)cands[i] * 256 * KB <= ws_size) { Tc = cands[i]; break; }
  }

  if (Tc > 0) {
    float* biasbuf = (float*)(ws + 4096);                    // 16 KB
    __hip_bfloat16* whT = (__hip_bfloat16*)(ws + 1 * MB);    // [4][1024][256] = 2 MB
    __hip_bfloat16* wxT0 = (__hip_bfloat16*)(ws + 3 * MB);   // [2][1024][256] = 1 MB
    __hip_bfloat16* wxT1 = (__hip_bfloat16*)(ws + 4 * MB);   // [2][1024][512] = 2 MB
    unsigned* hgs0 = (unsigned*)(ws + 6 * MB);               // 256 KB
    unsigned* hgs1 = (unsigned*)(ws + 6 * MB + 256 * KB);    // 256 KB
    unsigned* hflags0 = (unsigned*)(ws + 6 * MB + 512 * KB); // 256 B (hint flags L0)
    unsigned* hflags1 = (unsigned*)(ws + 6 * MB + 513 * KB); // 256 B (hint flags L1)
    float* cstate0 = (float*)(ws + 7 * MB);                  // 128 KB
    float* hstate0 = (float*)(ws + 7 * MB + 128 * KB);       // 128 KB
    float* cstate1 = (float*)(ws + 7 * MB + 256 * KB);       // 128 KB
    float* hstate1 = (float*)(ws + 7 * MB + 384 * KB);       // 128 KB
    __hip_bfloat16* seq0 = (__hip_bfloat16*)(ws + 8 * MB);   // [1024][64][512] = 64 MB
    __hip_bfloat16* xsl = (__hip_bfloat16*)(ws + 73 * MB);   // [2][Tc][4][8][256][8] bf16

    k_prep_small<<<1, 256, 0, stream>>>(bf0, bb0, bf1, bb1, flag, biasbuf);
    k_prepw<<<dim3(12, 16, 4), 256, 0, stream>>>(Wf0, Wb0, Wf1, Wb1, flag, whT, wxT0, wxT1);
    // zero both mailboxes + hint flags: kill stale tags
    hipMemsetAsync(hgs0, 0, 516 * KB, stream);

    const int P = Tn / Tc;
    const int Mrows = Tc * 64;
    const int ntiles = (Mrows / 128) * 16;
    // layer 0
    for (int p = 0; p < P; ++p) {
      const int s0 = p * Tc;
      const int t0f = s0, t0b = Tn - s0 - Tc;
      k_xproj3<256, true><<<ntiles, 256, 0, stream>>>(x, E, flag, nullptr, nullptr, wxT0, xsl,
                                                      Mrows, t0f, t0b);
      k_lstm_fast<true><<<64, 256, 0, stream>>>(whT, xsl, biasbuf, lengths, hgs0, hflags0,
                                                cstate0, hstate0, seq0, s0, Tc);
    }
    // layer 1
    for (int p = 0; p < P; ++p) {
      const int s0 = p * Tc;
      const int t0f = s0, t0b = Tn - s0 - Tc;
      k_xproj3<512, false><<<ntiles, 256, 0, stream>>>(
          x, E, flag, seq0 + (size_t)t0f * 64 * 512, seq0 + (size_t)t0b * 64 * 512, wxT1, xsl,
          Mrows, 0, 0);
      k_lstm_fast<false><<<64, 256, 0, stream>>>(whT + 2 * 1024 * 256, xsl, biasbuf + 2048,
                                                 lengths, hgs1, hflags1, cstate1, hstate1,
                                                 nullptr, s0, Tc);
    }
    k_fc<<<1, 128, 0, stream>>>(hstate1, Wfc, bfc, flag, d_out);
  } else {
    // slow fallback (round-2 passing path)
    __hip_bfloat16* seq0 = (__hip_bfloat16*)(ws + 64 * 1024);
    const size_t seq0_bytes = (size_t)Bn * Tn * 2 * Hn * sizeof(__hip_bfloat16);
    float* hfin = (float*)(ws + 64 * 1024 + seq0_bytes);
    k_lstm<Dn, true><<<2 * Bn, 256, 0, stream>>>(x, E, nullptr, Wf0, bf0, Wb0, bb0, lengths, flag,
                                                 seq0, nullptr);
    k_lstm<2 * Hn, false><<<2 * Bn, 256, 0, stream>>>(x, E, seq0, Wf1, bf1, Wb1, bb1, lengths,
                                                      flag, nullptr, hfin);
    k_fc<<<1, 128, 0, stream>>>(hfin, Wfc, bfc, flag, d_out);
  }
}

// Round 11
// 12032.371 us; speedup vs baseline: 2.0228x; 1.2389x over previous
//
#include <hip/hip_runtime.h>
#include <hip/hip_bf16.h>
#include <math.h>

// Problem constants: V=32000, D=256, H=256, L=2, C=2, B=64, T=1024, PAD=0
namespace {
constexpr int Bn = 64;
constexpr int Tn = 1024;
constexpr int Dn = 256;
constexpr int Hn = 256;
}

typedef __attribute__((ext_vector_type(8))) short short8;
typedef __attribute__((ext_vector_type(4))) float f32x4;

template <typename T>
__device__ __forceinline__ float ldf(const T* p, long i);
template <>
__device__ __forceinline__ float ldf<float>(const float* p, long i) { return p[i]; }
template <>
__device__ __forceinline__ float ldf<__hip_bfloat16>(const __hip_bfloat16* p, long i) {
  return __bfloat162float(p[i]);
}

// Fast gates: v_rcp_f32 instead of the IEEE div sequence (~10 ops each).
// 80 divisions/thread/step in the lstm gate phase -> ~0.5-0.7 us/wave saved.
// rel-err ~1 ulp; output is bf16 so rounding dominates.
__device__ __forceinline__ float sigmf(float x) {
  return __builtin_amdgcn_rcpf(1.0f + __expf(-x));
}
__device__ __forceinline__ float tanh_fast(float x) {
  return 1.0f - 2.0f * __builtin_amdgcn_rcpf(__expf(2.0f * x) + 1.0f);
}

// LDS-only barrier: orders all DS ops across the block WITHOUT draining
// outstanding global loads/stores (hipcc's __syncthreads emits a full
// s_waitcnt vmcnt(0)). lgkmcnt(0) + "memory" clobber covers LDS ordering;
// sched_barrier(0) pins against compiler reordering (rule #18).
__device__ __forceinline__ void lds_barrier() {
  asm volatile("s_waitcnt lgkmcnt(0)" ::: "memory");
  __builtin_amdgcn_sched_barrier(0);
  __builtin_amdgcn_s_barrier();
  __builtin_amdgcn_sched_barrier(0);
}

// ---------------------------------------------------------------------------
// Dtype detector (validated round 2: flag=1 -> f32 inputs).
// ---------------------------------------------------------------------------
__global__ void k_detect(const unsigned short* __restrict__ e, int* __restrict__ flag) {
  __shared__ int sbuf[256];
  int bad = 0;
  for (int i = threadIdx.x; i < 4096; i += 256) {
    const unsigned short v = e[i];
    const int ex = (v >> 7) & 0xFF;
    bad += (ex >= 137) ? 1 : 0;
  }
  sbuf[threadIdx.x] = bad;
  __syncthreads();
  for (int s = 128; s > 0; s >>= 1) {
    if (threadIdx.x < s) sbuf[threadIdx.x] += sbuf[threadIdx.x + s];
    __syncthreads();
  }
  if (threadIdx.x == 0) flag[0] = (sbuf[0] > 64) ? 1 : 0;
}

__global__ void k_lengths(const int* __restrict__ x, int* __restrict__ len) {
  const int b = blockIdx.x;
  int cnt = 0;
  for (int t = threadIdx.x; t < Tn; t += blockDim.x) cnt += (x[b * Tn + t] != 0) ? 1 : 0;
  __shared__ int sbuf[256];
  sbuf[threadIdx.x] = cnt;
  __syncthreads();
  for (int s = 128; s > 0; s >>= 1) {
    if (threadIdx.x < s) sbuf[threadIdx.x] += sbuf[threadIdx.x + s];
    __syncthreads();
  }
  if (threadIdx.x == 0) len[b] = sbuf[0];
}

// ===========================================================================
// FAST PATH
// ===========================================================================

// biases -> f32 [4][1024] (order: f0,b0,f1,b1).
__global__ void k_prep_small(const void* b0f, const void* b0b, const void* b1f, const void* b1b,
                             const int* __restrict__ flag, float* __restrict__ biasbuf) {
  const int tid = threadIdx.x;
  const bool isf32 = flag[0] != 0;
  for (int idx = tid; idx < 4096; idx += 256) {
    const int j = idx >> 10, col = idx & 1023;
    const void* src = (j == 0) ? b0f : (j == 1) ? b0b : (j == 2) ? b1f : b1b;
    biasbuf[idx] = isf32 ? ((const float*)src)[col]
                         : __bfloat162float(((const __hip_bfloat16*)src)[col]);
  }
}

// Transpose+convert W[(H+XK) x 1024] -> WhT bf16 [1024][256], WxT bf16 [1024][XK].
__global__ void k_prepw(const void* W0, const void* W1, const void* W2, const void* W3,
                        const int* __restrict__ flag, __hip_bfloat16* __restrict__ whT,
                        __hip_bfloat16* __restrict__ wxT0, __hip_bfloat16* __restrict__ wxT1) {
  const int j = blockIdx.z;
  const int rows = (j < 2) ? 512 : 768;
  const int bx = blockIdx.x;
  if (bx * 64 >= rows) return;
  const int by = blockIdx.y;
  const void* W = (j == 0) ? W0 : (j == 1) ? W1 : (j == 2) ? W2 : W3;
  const bool isf32 = flag[0] != 0;
  __shared__ float tile[64][65];
  const int tid = threadIdx.x;
  const int c = tid & 63, r4 = tid >> 6;
#pragma unroll
  for (int rep = 0; rep < 16; ++rep) {
    const int rr = r4 * 16 + rep;
    const size_t idx = (size_t)(bx * 64 + rr) * 1024 + by * 64 + c;
    tile[rr][c] = isf32 ? ((const float*)W)[idx]
                        : __bfloat162float(((const __hip_bfloat16*)W)[idx]);
  }
  __syncthreads();
  const int kk = tid & 63;
#pragma unroll
  for (int rep = 0; rep < 16; ++rep) {
    const int a = r4 * 16 + rep;
    const int n = by * 64 + a;
    const int k = bx * 64 + kk;
    const __hip_bfloat16 v = __float2bfloat16(tile[kk][a]);
    if (k < 256) {
      whT[(size_t)j * (1024 * 256) + (size_t)n * 256 + k] = v;
    } else {
      const int k2 = k - 256;
      if (j < 2)
        wxT0[(size_t)j * (1024 * 256) + (size_t)n * 256 + k2] = v;
      else
        wxT1[(size_t)(j - 2) * (1024 * 512) + (size_t)n * 512 + k2] = v;
    }
  }
}

// ---------------------------------------------------------------------------
// xproj GEMM v4 (validated rounds 2-6): 128x128 tile/block, B in LDS, A from
// global/gather; OUTPUT in the consumer-native layout of k_lstm_fast:
//   xp[d][tl][q 0..3][jv 0..7][tid 0..255][8 bf16]   (per (d,tl): 128 KB)
// Producer mapping (verified): tl = bx*2+(w>>1); jv = (by>>1)*2+(w&1);
//   q = (by&1)*2+(nt>>2); tid_c = (nt&3)*64+quad*16+l16; elem = mt2*4+r.
// ---------------------------------------------------------------------------
template <int K, bool GATHER>
__launch_bounds__(256, 2)
__global__ void k_xproj3(const int* __restrict__ x, const void* __restrict__ E,
                         const int* __restrict__ flag, const __hip_bfloat16* __restrict__ Af,
                         const __hip_bfloat16* __restrict__ Ab,
                         const __hip_bfloat16* __restrict__ WT,  // [2][1024][K]
                         __hip_bfloat16* __restrict__ xp,        // [2][Tc][4][8][256][8]
                         const int Mrows, const int t0f, const int t0b) {
  constexpr int KC = 256;
  __shared__ __hip_bfloat16 Btile[128][KC + 8];
  const int tix = blockIdx.x;
  const int by = tix & 7;
  const int dz = (tix >> 3) & 1;
  const int bx = tix >> 4;
  const int tid = threadIdx.x, w = tid >> 6, L = tid & 63, quad = L >> 4, l16 = L & 15;
  const __hip_bfloat16* __restrict__ WTd = WT + (size_t)dz * (1024 * K);
  __hip_bfloat16* __restrict__ o = xp + (size_t)dz * Mrows * 1024;

  f32x4 acc[2][8];
#pragma unroll
  for (int mt = 0; mt < 2; ++mt)
#pragma unroll
    for (int nt = 0; nt < 8; ++nt) {
      acc[mt][nt][0] = 0.f; acc[mt][nt][1] = 0.f; acc[mt][nt][2] = 0.f; acc[mt][nt][3] = 0.f;
    }

  const int row0 = bx * 128 + w * 32 + l16;  // a0 row; a1 = row0+16
  const __hip_bfloat16* arow0b = nullptr;
  const __hip_bfloat16* arow1b = nullptr;
  const float* arow0f = nullptr;
  const float* arow1f = nullptr;
  bool isf32 = false;
  if constexpr (GATHER) {
    isf32 = flag[0] != 0;
    const int t0 = (dz ? t0b : t0f) + (row0 >> 6), b0 = row0 & 63;
    const int r1 = row0 + 16;
    const int t1 = (dz ? t0b : t0f) + (r1 >> 6), b1 = r1 & 63;
    const int tok0 = x[b0 * Tn + t0];
    const int tok1 = x[b1 * Tn + t1];
    if (isf32) {
      arow0f = (const float*)E + (size_t)tok0 * Dn;
      arow1f = (const float*)E + (size_t)tok1 * Dn;
    } else {
      arow0b = (const __hip_bfloat16*)E + (size_t)tok0 * Dn;
      arow1b = (const __hip_bfloat16*)E + (size_t)tok1 * Dn;
    }
  } else {
    const __hip_bfloat16* A = dz ? Ab : Af;
    arow0b = A + (size_t)row0 * K;
    arow1b = A + (size_t)(row0 + 16) * K;
  }

  for (int ch = 0; ch < K / KC; ++ch) {
    if (ch) __syncthreads();
    // stage B chunk: 128 cols x 256 shorts
#pragma unroll
    for (int it = 0; it < 16; ++it) {
      const int idx = it * 256 + tid;
      const int col = idx >> 5, seg = idx & 31;
      *(short8*)&Btile[col][seg * 8] =
          *(const short8*)(WTd + (size_t)(by * 128 + col) * K + ch * KC + seg * 8);
    }
    __syncthreads();

#pragma unroll
    for (int kc = 0; kc < 8; ++kc) {
      short8 a0, a1;
      if constexpr (GATHER) {
        if (isf32) {
#pragma unroll
          for (int jj = 0; jj < 8; ++jj) {
            __hip_bfloat16 h0 = __float2bfloat16(arow0f[kc * 32 + quad * 8 + jj]);
            __hip_bfloat16 h1 = __float2bfloat16(arow1f[kc * 32 + quad * 8 + jj]);
            a0[jj] = *(const short*)&h0;
            a1[jj] = *(const short*)&h1;
          }
        } else {
          a0 = *(const short8*)(arow0b + kc * 32 + quad * 8);
          a1 = *(const short8*)(arow1b + kc * 32 + quad * 8);
        }
      } else {
        a0 = *(const short8*)(arow0b + ch * KC + kc * 32 + quad * 8);
        a1 = *(const short8*)(arow1b + ch * KC + kc * 32 + quad * 8);
      }
#pragma unroll
      for (int nt = 0; nt < 8; ++nt) {
        const short8 b = *(const short8*)&Btile[nt * 16 + l16][kc * 32 + quad * 8];
        acc[0][nt] = __builtin_amdgcn_mfma_f32_16x16x32_bf16(a0, b, acc[0][nt], 0, 0, 0);
        acc[1][nt] = __builtin_amdgcn_mfma_f32_16x16x32_bf16(a1, b, acc[1][nt], 0, 0, 0);
      }
    }
  }

  // --- epilogue: consumer-native layout, fully coalesced 16B stores ---
  {
    const int tl = bx * 2 + (w >> 1);
    const int jv = (by >> 1) * 2 + (w & 1);
    const int qbase = (by & 1) << 1;
    __hip_bfloat16* __restrict__ ob = o + (size_t)tl * 65536 + (size_t)jv * 2048;
#pragma unroll
    for (int nt = 0; nt < 8; ++nt) {
      const int q_ = qbase + (nt >> 2);
      const int tid_c = (nt & 3) * 64 + quad * 16 + l16;
      short8 sv;
#pragma unroll
      for (int r = 0; r < 4; ++r) {
        __hip_bfloat16 h0 = __float2bfloat16(acc[0][nt][r]);
        __hip_bfloat16 h1 = __float2bfloat16(acc[1][nt][r]);
        sv[r] = *(const short*)&h0;
        sv[4 + r] = *(const short*)&h1;
      }
      *(short8*)(ob + (size_t)q_ * 16384 + tid_c * 8) = sv;
    }
  }
}

// ---------------------------------------------------------------------------
// Phased recurrent layer v12: round-10 body (hint flags + validated tagged
// sweep + XCD placement + LDS-only barriers) with two compute-side fixes:
//   * rcp-based gates (80 IEEE div sequences/thread/step -> 80 v_rcp)
//   * DOUBLE-BUFFERED h_lds: step s reads/fills buf[(s-1)&1], writes local
//     h(s) to buf[s&1] -> ONE barrier per step instead of two.
//     Hazards: fill-cols (w!=q) disjoint from local-cols (q); alternating
//     buffers make cross-step accesses disjoint; the single in-exchange
//     barrier + per-wave lgkmcnt(0) drain covers the remaining ordering.
// Protocol (tags, parity slots, hint flags) byte-identical to round 10.
// ---------------------------------------------------------------------------
template <bool WRITE_SEQ>
__launch_bounds__(256, 1) __global__
void k_lstm_fast(const __hip_bfloat16* __restrict__ WhT,   // [2][1024][256] this layer
                 const __hip_bfloat16* __restrict__ xproj,  // [2][Tc][4][8][256][8] bf16
                 const float* __restrict__ biasL,           // [2][1024] this layer
                 const int* __restrict__ lengths,
                 unsigned* __restrict__ hgs,     // [2 d][2 par][4 q][64 b][64 u] u32
                 unsigned* __restrict__ hflags,  // [2 d][2 par][4 q][4 w] u32 hint flags
                 float* __restrict__ cstate, float* __restrict__ hstate,  // [2][64][256]
                 __hip_bfloat16* __restrict__ seq0,         // [T][64][512]
                 const int s0, const int Tc) {
  // XCD-aware remap: worker iff (bid&7)<2 && (bid>>3)<4; d = bid&7, q = bid>>3.
  const int xcd = blockIdx.x & 7;
  const int kq = blockIdx.x >> 3;
  if (xcd >= 2 || kq >= 4) return;
  const int d = xcd;
  const int q = kq;
  const int tid = threadIdx.x;
  const int w = tid >> 6, L = tid & 63, quad = L >> 4, l16 = L & 15;
  const int u = q * 64 + w * 16 + l16;

  __shared__ __hip_bfloat16 h_lds[2][64][272];
  for (int idx = tid; idx < 2 * 64 * 272; idx += 256)
    (&h_lds[0][0][0])[idx] = __float2bfloat16(0.0f);

  const __hip_bfloat16* __restrict__ Wd = WhT + (size_t)d * (1024 * 256);
  short8 wfrag[4][8];
#pragma unroll
  for (int g = 0; g < 4; ++g)
#pragma unroll
    for (int kc = 0; kc < 8; ++kc)
      wfrag[g][kc] = *(const short8*)(Wd + (size_t)(g * 256 + u) * 256 + kc * 32 + quad * 8);

  float bz[4];
#pragma unroll
  for (int g = 0; g < 4; ++g) bz[g] = biasL[d * 1024 + g * 256 + u];

  float c_reg[16], h_reg[16];
  int len_b[16];
#pragma unroll
  for (int mt = 0; mt < 4; ++mt)
#pragma unroll
    for (int r = 0; r < 4; ++r) {
      const int idx = mt * 4 + r;
      const int b = mt * 16 + quad * 4 + r;
      len_b[idx] = lengths[b];
      if (s0 == 0) {
        c_reg[idx] = 0.0f;
        h_reg[idx] = 0.0f;
      } else {
        c_reg[idx] = cstate[((size_t)(d * 64 + b) << 8) + u];
        h_reg[idx] = hstate[((size_t)(d * 64 + b) << 8) + u];
      }
    }
  __syncthreads();
  // h(s0-1) lives in buf[(s0-1)&1]
  {
    const int ib = (s0 - 1) & 1;
#pragma unroll
    for (int mt = 0; mt < 4; ++mt)
#pragma unroll
      for (int r = 0; r < 4; ++r)
        h_lds[ib][mt * 16 + quad * 4 + r][u] = __float2bfloat16(h_reg[mt * 4 + r]);
  }
  __syncthreads();

  // base of this (d, q, tid)'s xproj stream
  const __hip_bfloat16* __restrict__ xq =
      xproj + (size_t)d * Tc * 65536 + (size_t)q * 16384 + (size_t)tid * 8;

  for (int sl = 0; sl < Tc; ++sl) {
    const int s = s0 + sl;
    const int t = d ? (Tn - 1 - s) : s;
    const int tl = d ? (Tc - 1 - sl) : sl;
    const int pb = (s - 1) & 1;  // buffer holding h(s-1)
    const int cb = s & 1;        // buffer receiving h(s)

    // 1. issue coalesced xproj loads (consumed after the exchange -> latency
    //    hides under the spin; only 32 VGPRs live across it)
    short8 xv[8];
    {
      const __hip_bfloat16* __restrict__ src = xq + (size_t)tl * 65536;
#pragma unroll
      for (int jv = 0; jv < 8; ++jv) xv[jv] = *(const short8*)(src + jv * 2048);
    }

    // 2. exchange: hint-flag pre-spin, then the validated tagged sweep
    if (s > 0) {
      if (w != q) {
        const unsigned exp = (unsigned)s;
        // 2a. cheap hint spin: 4x4B uniform loads per retry
        {
          const unsigned* __restrict__ f4 =
              hflags + (((d * 2 + ((s - 1) & 1)) * 4 + w) * 4);
          for (;;) {
            const unsigned f0 =
                __hip_atomic_load(f4 + 0, __ATOMIC_RELAXED, __HIP_MEMORY_SCOPE_AGENT);
            const unsigned f1 =
                __hip_atomic_load(f4 + 1, __ATOMIC_RELAXED, __HIP_MEMORY_SCOPE_AGENT);
            const unsigned f2 =
                __hip_atomic_load(f4 + 2, __ATOMIC_RELAXED, __HIP_MEMORY_SCOPE_AGENT);
            const unsigned f3 =
                __hip_atomic_load(f4 + 3, __ATOMIC_RELAXED, __HIP_MEMORY_SCOPE_AGENT);
            if (f0 >= exp && f1 >= exp && f2 >= exp && f3 >= exp) break;
            __builtin_amdgcn_s_sleep(1);
          }
        }
        // 2b. validated tagged-payload sweep (normally single pass now)
        const unsigned long long* __restrict__ src64 =
            (const unsigned long long*)(hgs + ((((size_t)d * 2 + ((s - 1) & 1)) * 4 + w) << 12));
        unsigned long long v[32];
        unsigned pend = 0xFFFFFFFFu;
        int tries = 0;
        do {
          if (tries++) __builtin_amdgcn_s_sleep(1);
#pragma unroll
          for (int i = 0; i < 32; ++i)
            if (pend & (1u << i))
              v[i] = __hip_atomic_load(src64 + i * 64 + L, __ATOMIC_RELAXED,
                                       __HIP_MEMORY_SCOPE_AGENT);
#pragma unroll
          for (int i = 0; i < 32; ++i)
            if (pend & (1u << i)) {
              const unsigned lo = (unsigned)v[i], hi = (unsigned)(v[i] >> 32);
              if ((lo >> 16) == exp && (hi >> 16) == exp) pend &= ~(1u << i);
            }
        } while (pend);
#pragma unroll
        for (int i = 0; i < 32; ++i) {
          const int j = i * 64 + L;
          const unsigned lo = (unsigned)v[i], hi = (unsigned)(v[i] >> 32);
          const unsigned packed = (lo & 0xFFFFu) | (hi << 16);
          *(unsigned*)&h_lds[pb][j >> 5][w * 64 + (j & 31) * 2] = packed;
        }
      }
      lds_barrier();  // the ONLY barrier per step (LDS-only, no vmcnt drain)
    }

    // 3. unpack xproj + f32 bias -> acc
    f32x4 acc[4][4];
#pragma unroll
    for (int mt = 0; mt < 4; ++mt)
#pragma unroll
      for (int g = 0; g < 4; ++g) {
        const short8 v = xv[g * 2 + (mt >> 1)];
#pragma unroll
        for (int r = 0; r < 4; ++r) {
          const short sv = v[(mt & 1) * 4 + r];
          acc[mt][g][r] = __bfloat162float(*(const __hip_bfloat16*)&sv) + bz[g];
        }
      }

    // 4. z += h @ Wh   (reads buf[pb] = h(s-1))
#pragma unroll
    for (int kc = 0; kc < 8; ++kc) {
#pragma unroll
      for (int mt = 0; mt < 4; ++mt) {
        const short8 a = *(const short8*)&h_lds[pb][mt * 16 + l16][kc * 32 + quad * 8];
#pragma unroll
        for (int g = 0; g < 4; ++g)
          acc[mt][g] =
              __builtin_amdgcn_mfma_f32_16x16x32_bf16(a, wfrag[g][kc], acc[mt][g], 0, 0, 0);
      }
    }

    // 5. gates + state update; publish tagged slice (write-through u32)
    unsigned* __restrict__ dst32 = hgs + ((((size_t)d * 2 + (s & 1)) * 4 + q) << 12);
    const unsigned tag = ((unsigned)(s + 1)) << 16;
    __hip_bfloat16 hbf[16];
#pragma unroll
    for (int mt = 0; mt < 4; ++mt)
#pragma unroll
      for (int r = 0; r < 4; ++r) {
        const int idx = mt * 4 + r, b = mt * 16 + quad * 4 + r;
        const float fg = sigmf(acc[mt][0][r]);
        const float ig = sigmf(acc[mt][1][r]);
        const float gg = tanh_fast(acc[mt][2][r]);
        const float og = sigmf(acc[mt][3][r]);
        const float cn = fg * c_reg[idx] + ig * gg;
        const float hn = og * tanh_fast(cn);
        if (t < len_b[idx]) {
          c_reg[idx] = cn;
          h_reg[idx] = hn;
        }
        hbf[idx] = __float2bfloat16(h_reg[idx]);
        __hip_atomic_store(dst32 + b * 64 + w * 16 + l16,
                           tag | (unsigned)*(unsigned short*)&hbf[idx], __ATOMIC_RELAXED,
                           __HIP_MEMORY_SCOPE_AGENT);
      }

    // hint flag: this wave's 16 payload stores are issued (program order);
    // hint-only, correctness stays with the tag sweep.
    if (L == 0)
      __hip_atomic_store(hflags + (((d * 2 + (s & 1)) * 4 + q) * 4 + w),
                         (unsigned)(s + 1), __ATOMIC_RELAXED, __HIP_MEMORY_SCOPE_AGENT);

    // 6. local h(s) -> buf[cb]; no barrier needed (readers of buf[cb] are
    //    gated by the next step's barrier; columns disjoint from fills)
#pragma unroll
    for (int mt = 0; mt < 4; ++mt)
#pragma unroll
      for (int r = 0; r < 4; ++r)
        h_lds[cb][mt * 16 + quad * 4 + r][u] = hbf[mt * 4 + r];

    if (WRITE_SEQ) {
#pragma unroll
      for (int mt = 0; mt < 4; ++mt)
#pragma unroll
        for (int r = 0; r < 4; ++r) {
          const int b = mt * 16 + quad * 4 + r;
          seq0[((size_t)t * 64 + b) * 512 + d * 256 + u] = hbf[mt * 4 + r];
        }
    }
  }

#pragma unroll
  for (int mt = 0; mt < 4; ++mt)
#pragma unroll
    for (int r = 0; r < 4; ++r) {
      const int idx = mt * 4 + r, b = mt * 16 + quad * 4 + r;
      cstate[((size_t)(d * 64 + b) << 8) + u] = c_reg[idx];
      hstate[((size_t)(d * 64 + b) << 8) + u] = h_reg[idx];
    }
}

// ===========================================================================
// SLOW FALLBACK PATH (round-2 passing version, used when ws is too small)
// ===========================================================================
template <typename TW, int XK, bool WRITE_SEQ>
__device__ __forceinline__ void lstm_body(const int* __restrict__ x, const TW* __restrict__ E,
                                          const __hip_bfloat16* __restrict__ seq_in,
                                          const TW* __restrict__ W, const TW* __restrict__ bias,
                                          const int len, const int b, const int dir,
                                          __hip_bfloat16* __restrict__ seq_out,
                                          float* __restrict__ hfin) {
  const int j = threadIdx.x;
  __shared__ float h[Hn];
  __shared__ float xb[XK];
  float hj = 0.0f, cj = 0.0f;
  h[j] = 0.0f;
  const float bfj = ldf(bias, j);
  const float bij = ldf(bias, Hn + j);
  const float bgj = ldf(bias, 2 * Hn + j);
  const float boj = ldf(bias, 3 * Hn + j);
  __syncthreads();
  for (int s = 0; s < Tn; ++s) {
    const int t = dir ? (Tn - 1 - s) : s;
    const bool active = (t < len);
    if (active) {
      if constexpr (XK == Dn) {
        const int tok = x[b * Tn + t];
        xb[j] = ldf(E, (long)tok * Dn + j);
      } else {
        const long base = ((long)(b * Tn + t)) * (2 * Hn);
        xb[j] = __bfloat162float(seq_in[base + j]);
        xb[j + Hn] = __bfloat162float(seq_in[base + j + Hn]);
      }
      __syncthreads();
      float af = bfj, ai = bij, ag = bgj, ao = boj;
#pragma unroll 4
      for (int k = 0; k < Hn; ++k) {
        const float hk = h[k];
        const long r = (long)k * (4 * Hn);
        af += hk * ldf(W, r + j);
        ai += hk * ldf(W, r + Hn + j);
        ag += hk * ldf(W, r + 2 * Hn + j);
        ao += hk * ldf(W, r + 3 * Hn + j);
      }
#pragma unroll 4
      for (int k = 0; k < XK; ++k) {
        const float xk = xb[k];
        const long r = (long)(Hn + k) * (4 * Hn);
        af += xk * ldf(W, r + j);
        ai += xk * ldf(W, r + Hn + j);
        ag += xk * ldf(W, r + 2 * Hn + j);
        ao += xk * ldf(W, r + 3 * Hn + j);
      }
      const float fg = 1.0f / (1.0f + expf(-af));
      const float ig = 1.0f / (1.0f + expf(-ai));
      const float gg = tanhf(ag);
      const float og = 1.0f / (1.0f + expf(-ao));
      const float cn = fg * cj + ig * gg;
      const float hn = og * tanhf(cn);
      __syncthreads();
      hj = hn;
      cj = cn;
      h[j] = hn;
      __syncthreads();
    }
    if constexpr (WRITE_SEQ) {
      seq_out[((long)(b * Tn + t)) * (2 * Hn) + dir * Hn + j] = __float2bfloat16(hj);
    }
  }
  if constexpr (!WRITE_SEQ) hfin[(dir * Bn + b) * Hn + j] = hj;
}

template <int XK, bool WRITE_SEQ>
__global__ void k_lstm(const int* __restrict__ x, const void* __restrict__ E,
                       const __hip_bfloat16* __restrict__ seq_in, const void* __restrict__ Wf,
                       const void* __restrict__ bf, const void* __restrict__ Wb,
                       const void* __restrict__ bb, const int* __restrict__ lengths,
                       const int* __restrict__ flag, __hip_bfloat16* __restrict__ seq_out,
                       float* __restrict__ hfin) {
  const int b = blockIdx.x & (Bn - 1);
  const int dir = blockIdx.x >> 6;
  const int len = lengths[b];
  const void* W = dir ? Wb : Wf;
  const void* bias = dir ? bb : bf;
  if (flag[0]) {
    lstm_body<float, XK, WRITE_SEQ>(x, (const float*)E, seq_in, (const float*)W,
                                    (const float*)bias, len, b, dir, seq_out, hfin);
  } else {
    lstm_body<__hip_bfloat16, XK, WRITE_SEQ>(x, (const __hip_bfloat16*)E, seq_in,
                                             (const __hip_bfloat16*)W, (const __hip_bfloat16*)bias,
                                             len, b, dir, seq_out, hfin);
  }
}

// ---------------------------------------------------------------------------
template <typename TW>
__device__ __forceinline__ void fc_body(const float* __restrict__ hfin, const TW* __restrict__ Wfc,
                                        const TW* __restrict__ bfc, TW* __restrict__ out) {
  const int idx = threadIdx.x;
  const int b = idx >> 1;
  const int cc = idx & 1;
  float acc = ldf(bfc, cc);
  for (int k = 0; k < Hn; ++k) acc += hfin[(0 * Bn + b) * Hn + k] * ldf(Wfc, k * 2 + cc);
  for (int k = 0; k < Hn; ++k) acc += hfin[(1 * Bn + b) * Hn + k] * ldf(Wfc, (Hn + k) * 2 + cc);
  if constexpr (sizeof(TW) == 2) {
    out[b * 2 + cc] = __float2bfloat16(acc);
  } else {
    out[b * 2 + cc] = acc;
  }
}

__global__ void k_fc(const float* __restrict__ hfin, const void* __restrict__ Wfc,
                     const void* __restrict__ bfc, const int* __restrict__ flag,
                     void* __restrict__ out) {
  if (flag[0]) {
    fc_body<float>(hfin, (const float*)Wfc, (const float*)bfc, (float*)out);
  } else {
    fc_body<__hip_bfloat16>(hfin, (const __hip_bfloat16*)Wfc, (const __hip_bfloat16*)bfc,
                            (__hip_bfloat16*)out);
  }
}

// ---------------------------------------------------------------------------
extern "C" void kernel_launch(void* const* d_in, const int* in_sizes, int n_in,
                              void* d_out, int out_size, void* d_ws, size_t ws_size,
                              hipStream_t stream) {
  const int* x = (const int*)d_in[0];
  const void* E = d_in[1];
  const void* Wf0 = d_in[2];
  const void* bf0 = d_in[3];
  const void* Wb0 = d_in[4];
  const void* bb0 = d_in[5];
  const void* Wf1 = d_in[6];
  const void* bf1 = d_in[7];
  const void* Wb1 = d_in[8];
  const void* bb1 = d_in[9];
  const void* Wfc = d_in[10];
  const void* bfc = d_in[11];

  char* ws = (char*)d_ws;
  int* flag = (int*)ws;             // @0
  int* lengths = (int*)(ws + 256);

  const size_t MB = 1ull << 20;
  const size_t KB = 1024;

  k_detect<<<1, 256, 0, stream>>>((const unsigned short*)E, flag);
  k_lengths<<<Bn, 256, 0, stream>>>(x, lengths);

  // fixed 73 MB (weights/state/seq0) + one bf16 xproj slot Tc*256KB (reused L0/L1)
  int Tc = 0;
  {
    const size_t fixed = 73 * MB;
    const int cands[7] = {1024, 512, 256, 128, 64, 32, 16};
    for (int i = 0; i < 7; ++i)
      if (fixed + (size_t)cands[i] * 256 * KB <= ws_size) { Tc = cands[i]; break; }
  }

  if (Tc > 0) {
    float* biasbuf = (float*)(ws + 4096);                    // 16 KB
    __hip_bfloat16* whT = (__hip_bfloat16*)(ws + 1 * MB);    // [4][1024][256] = 2 MB
    __hip_bfloat16* wxT0 = (__hip_bfloat16*)(ws + 3 * MB);   // [2][1024][256] = 1 MB
    __hip_bfloat16* wxT1 = (__hip_bfloat16*)(ws + 4 * MB);   // [2][1024][512] = 2 MB
    unsigned* hgs0 = (unsigned*)(ws + 6 * MB);               // 256 KB
    unsigned* hgs1 = (unsigned*)(ws + 6 * MB + 256 * KB);    // 256 KB
    unsigned* hflags0 = (unsigned*)(ws + 6 * MB + 512 * KB); // 256 B (hint flags L0)
    unsigned* hflags1 = (unsigned*)(ws + 6 * MB + 513 * KB); // 256 B (hint flags L1)
    float* cstate0 = (float*)(ws + 7 * MB);                  // 128 KB
    float* hstate0 = (float*)(ws + 7 * MB + 128 * KB);       // 128 KB
    float* cstate1 = (float*)(ws + 7 * MB + 256 * KB);       // 128 KB
    float* hstate1 = (float*)(ws + 7 * MB + 384 * KB);       // 128 KB
    __hip_bfloat16* seq0 = (__hip_bfloat16*)(ws + 8 * MB);   // [1024][64][512] = 64 MB
    __hip_bfloat16* xsl = (__hip_bfloat16*)(ws + 73 * MB);   // [2][Tc][4][8][256][8] bf16

    k_prep_small<<<1, 256, 0, stream>>>(bf0, bb0, bf1, bb1, flag, biasbuf);
    k_prepw<<<dim3(12, 16, 4), 256, 0, stream>>>(Wf0, Wb0, Wf1, Wb1, flag, whT, wxT0, wxT1);
    // zero both mailboxes + hint flags: kill stale tags
    hipMemsetAsync(hgs0, 0, 516 * KB, stream);

    const int P = Tn / Tc;
    const int Mrows = Tc * 64;
    const int ntiles = (Mrows / 128) * 16;
    // layer 0
    for (int p = 0; p < P; ++p) {
      const int s0 = p * Tc;
      const int t0f = s0, t0b = Tn - s0 - Tc;
      k_xproj3<256, true><<<ntiles, 256, 0, stream>>>(x, E, flag, nullptr, nullptr, wxT0, xsl,
                                                      Mrows, t0f, t0b);
      k_lstm_fast<true><<<64, 256, 0, stream>>>(whT, xsl, biasbuf, lengths, hgs0, hflags0,
                                                cstate0, hstate0, seq0, s0, Tc);
    }
    // layer 1
    for (int p = 0; p < P; ++p) {
      const int s0 = p * Tc;
      const int t0f = s0, t0b = Tn - s0 - Tc;
      k_xproj3<512, false><<<ntiles, 256, 0, stream>>>(
          x, E, flag, seq0 + (size_t)t0f * 64 * 512, seq0 + (size_t)t0b * 64 * 512, wxT1, xsl,
          Mrows, 0, 0);
      k_lstm_fast<false><<<64, 256, 0, stream>>>(whT + 2 * 1024 * 256, xsl, biasbuf + 2048,
                                                 lengths, hgs1, hflags1, cstate1, hstate1,
                                                 nullptr, s0, Tc);
    }
    k_fc<<<1, 128, 0, stream>>>(hstate1, Wfc, bfc, flag, d_out);
  } else {
    // slow fallback (round-2 passing path)
    __hip_bfloat16* seq0 = (__hip_bfloat16*)(ws + 64 * 1024);
    const size_t seq0_bytes = (size_t)Bn * Tn * 2 * Hn * sizeof(__hip_bfloat16);
    float* hfin = (float*)(ws + 64 * 1024 + seq0_bytes);
    k_lstm<Dn, true><<<2 * Bn, 256, 0, stream>>>(x, E, nullptr, Wf0, bf0, Wb0, bb0, lengths, flag,
                                                 seq0, nullptr);
    k_lstm<2 * Hn, false><<<2 * Bn, 256, 0, stream>>>(x, E, seq0, Wf1, bf1, Wb1, bb1, lengths,
                                                      flag, nullptr, hfin);
    k_fc<<<1, 128, 0, stream>>>(hfin, Wfc, bfc, flag, d_out);
  }
}